// Round 5
// baseline (468.767 us; speedup 1.0000x reference)
//
#include <hip/hip_runtime.h>

typedef __bf16 bf16;
typedef bf16 bf16x8 __attribute__((ext_vector_type(8)));
typedef bf16 bf16x4 __attribute__((ext_vector_type(4)));
typedef float f32x4 __attribute__((ext_vector_type(4)));

constexpr int NN = 8192;   // nodes
constexpr int DD = 512;    // gnn dim
constexpr size_t PSZB = (size_t)NN * DD * 2;   // 8 MB, one bf16 [NN][DD] buffer
constexpr size_t PSZE = (size_t)NN * DD;       // elements
constexpr int NS = 4;                          // split-K factor

static __device__ inline bf16x8 cvt8(const float* __restrict__ p) {
  f32x4 a = *(const f32x4*)p;
  f32x4 b = *(const f32x4*)(p + 4);
  bf16x8 r;
  r[0] = (bf16)a[0]; r[1] = (bf16)a[1]; r[2] = (bf16)a[2]; r[3] = (bf16)a[3];
  r[4] = (bf16)b[0]; r[5] = (bf16)b[1]; r[6] = (bf16)b[2]; r[7] = (bf16)b[3];
  return r;
}

// async global->LDS, 16B per lane, dest = wave-uniform base + lane*16
#define GLDS(g, l) __builtin_amdgcn_global_load_lds( \
    (const __attribute__((address_space(1))) unsigned int*)(const void*)(g), \
    (__attribute__((address_space(3))) unsigned int*)(void*)(l), 16, 0, 0)

// ---------------- converts ----------------

__global__ __launch_bounds__(256) void convert_w_kernel(
    const float* __restrict__ a, const float* __restrict__ b,
    bf16* __restrict__ ao, bf16* __restrict__ bo) {
  int i8 = ((int)blockIdx.x * 256 + (int)threadIdx.x) * 8;
  if (i8 < DD * DD) {
    *(bf16x8*)&ao[i8] = cvt8(a + i8);
  } else {
    int j = i8 - DD * DD;
    *(bf16x8*)&bo[j] = cvt8(b + j);
  }
}

// labels f32 [NN][DD] -> xb bf16 [NN][DD] and xbT bf16 [DD][NN] (64x64 LDS tiles)
__global__ __launch_bounds__(256) void convert_x_kernel(
    const float* __restrict__ src, bf16* __restrict__ xb, bf16* __restrict__ xbT) {
  __shared__ __align__(16) float tile[64][68];
  const int tid = (int)threadIdx.x;
  const int r0 = (int)blockIdx.x * 64;
  const int c0 = (int)blockIdx.y * 64;
#pragma unroll
  for (int p = 0; p < 4; ++p) {
    int row = p * 16 + (tid >> 4);
    int col = (tid & 15) * 4;
    *(f32x4*)&tile[row][col] = *(const f32x4*)&src[(size_t)(r0 + row) * DD + c0 + col];
  }
  __syncthreads();
#pragma unroll
  for (int p = 0; p < 4; ++p) {
    int row = p * 16 + (tid >> 4);
    int col = (tid & 15) * 4;
    f32x4 v = *(const f32x4*)&tile[row][col];
    bf16x4 o;
    o[0] = (bf16)v[0]; o[1] = (bf16)v[1]; o[2] = (bf16)v[2]; o[3] = (bf16)v[3];
    *(bf16x4*)&xb[(size_t)(r0 + row) * DD + c0 + col] = o;
  }
  {
    int c = tid >> 2;
    int rp = (tid & 3) * 16;
    bf16x8 o0, o1;
#pragma unroll
    for (int j = 0; j < 8; ++j) o0[j] = (bf16)tile[rp + j][c];
#pragma unroll
    for (int j = 0; j < 8; ++j) o1[j] = (bf16)tile[rp + 8 + j][c];
    *(bf16x8*)&xbT[(size_t)(c0 + c) * NN + r0 + rp] = o0;
    *(bf16x8*)&xbT[(size_t)(c0 + c) * NN + r0 + rp + 8] = o1;
  }
}

// ---------------- shared GEMM1 pieces ----------------
// XCD remap: both cb-blocks of an (p,s) A-slice on the same XCD; B-slice (cb,s)
// confined to 2 XCDs -> L2-resident.
#define G1_DECODE()                                        \
  const int bid  = (int)blockIdx.x;                        \
  const int xcd  = bid & 7, ii = bid >> 3;                 \
  const int cb   = ii & 1;                                 \
  const int jj_  = xcd + 8 * (ii >> 1);                    \
  const int p    = jj_ >> 2;                               \
  const int s    = jj_ & 3;                                \
  const int prow0 = p * 256;                               \
  const int bcol0 = cb * 256;                              \
  const int kb    = s * 2048;                              \
  bf16* __restrict__ P = pbase + (size_t)s * PSZE;         \
  const int tid  = (int)threadIdx.x;                       \
  const int lane = tid & 63;                               \
  const int wave = tid >> 6;                               \
  const int wr   = wave >> 2;                              \
  const int wc   = wave & 3;                               \
  const int fr   = lane & 15, fq = lane >> 4;              \
  const int srow = lane >> 3;                              \
  const int scol = ((lane & 7) ^ srow) * 8;  /* pre-swizzled GLDS source slot */

#define LOAD_Bv(base, kk)                                                  \
  _Pragma("unroll") for (int n = 0; n < 4; ++n) {                          \
    int rowl = wc * 64 + n * 16 + fr;                                      \
    int slot = ((kk) * 4 + fq) ^ (rowl & 7);                               \
    bv[kk][n] = *(const bf16x8*)&(base)[rowl * 64 + slot * 8];             \
  }
#define LOAD_A2v(base, h, kk)                                              \
  _Pragma("unroll") for (int u = 0; u < 2; ++u)                            \
  _Pragma("unroll") for (int j2 = 0; j2 < 2; ++j2) {                       \
    int rowl = ((h) * 2 + u) * 64 + wr * 32 + j2 * 16 + fr;                \
    int slot = ((kk) * 4 + fq) ^ (rowl & 7);                               \
    afx[u][j2] = *(const bf16x8*)&(base)[rowl * 64 + slot * 8];            \
  }
#define HMFMA(h, kk)                                                       \
  __builtin_amdgcn_s_setprio(1);                                           \
  _Pragma("unroll") for (int u = 0; u < 2; ++u)                            \
  _Pragma("unroll") for (int j2 = 0; j2 < 2; ++j2)                         \
  _Pragma("unroll") for (int n = 0; n < 4; ++n)                            \
    acc[((h) * 2 + u) * 2 + j2][n] = __builtin_amdgcn_mfma_f32_16x16x32_bf16( \
        afx[u][j2], bv[kk][n], acc[((h) * 2 + u) * 2 + j2][n], 0, 0, 0);   \
  __builtin_amdgcn_s_setprio(0);

#define G1_EPILOGUE()                                                      \
  _Pragma("unroll") for (int m = 0; m < 8; ++m)                            \
  _Pragma("unroll") for (int n = 0; n < 4; ++n)                            \
  _Pragma("unroll") for (int r = 0; r < 4; ++r) {                          \
    int row = prow0 + (m >> 1) * 64 + wr * 32 + (m & 1) * 16 + fq * 4 + r; \
    int col = bcol0 + wc * 64 + n * 16 + fr;                               \
    P[(size_t)row * DD + col] = (bf16)acc[m][n][r];                        \
  }

// ---------------- GEMM1 steady: P_s = bf16( adjb[:,ks:ke] @ x[ks:ke,:] ) ----------------
__device__ __forceinline__ void stage_half(const bf16* __restrict__ g, int grow0, int k0,
                                           bf16* smbase, int wave, int lane) {
#pragma unroll
  for (int i = 0; i < 2; ++i) {
    int c = wave * 2 + i;                                    // chunk 0..15, 1 KB each
    int row = grow0 + c * 8 + (lane >> 3);
    int col = k0 + (((lane & 7) ^ ((lane >> 3) & 7)) << 3);  // pre-swizzled source slot
    GLDS(g + (size_t)row * NN + col, smbase + c * 512);
  }
}

__global__ __launch_bounds__(512, 2)
void gemm1_kernel(const bf16* __restrict__ adjb, const bf16* __restrict__ xbT,
                  bf16* __restrict__ pbase) {
  __shared__ __align__(16) bf16 sm[65536];   // [par][A 16384 | B 16384], 128 KiB
  G1_DECODE();

  f32x4 acc[8][4] = {};

#define A_OFF(par) ((par) * 32768)
#define B_OFF(par) ((par) * 32768 + 16384)
#define STAGE_A(tile, half, par) \
  stage_half(adjb, prow0 + (half) * 128, kb + ((tile) & 31) * 64, \
             sm + A_OFF(par) + (half) * 8192, wave, lane)
#define STAGE_B(tile, half, par) \
  stage_half(xbT, bcol0 + (half) * 128, kb + ((tile) & 31) * 64, \
             sm + B_OFF(par) + (half) * 8192, wave, lane)
#define BARRIER() __builtin_amdgcn_s_barrier(); __builtin_amdgcn_sched_barrier(0)

  // prologue (14 loads): B(0), Ah0(0), Ah1(0), B(1), Ah0(1)
  STAGE_B(0, 0, 0); STAGE_B(0, 1, 0); STAGE_A(0, 0, 0); STAGE_A(0, 1, 0);
  STAGE_B(1, 0, 1); STAGE_B(1, 1, 1); STAGE_A(1, 0, 1);

  bf16x8 bv[2][4], afx[2][2];

  // issue pattern per phase: P1:2 (Ah1 t+1), P2:0, P3:2 (Bh0 t+2), P4:4 (Bh1,Ah0 t+2)
  // P1 needs Ah0(t): 8 newer loads after it -> vmcnt(8)
  // P3 needs Ah1(t): 8 newer loads after it -> vmcnt(8)
  int par = 0;
  for (int t = 0; t < 32; ++t, par ^= 1) {
    asm volatile("s_waitcnt vmcnt(8)" ::: "memory");
    BARRIER();
    LOAD_Bv(sm + B_OFF(par), 0);
    LOAD_A2v(sm + A_OFF(par), 0, 0);
    STAGE_A(t + 1, 1, par ^ 1);
    HMFMA(0, 0);

    BARRIER();
    LOAD_Bv(sm + B_OFF(par), 1);
    LOAD_A2v(sm + A_OFF(par), 0, 1);
    HMFMA(0, 1);

    asm volatile("s_waitcnt vmcnt(8)" ::: "memory");
    BARRIER();
    LOAD_A2v(sm + A_OFF(par), 1, 0);
    STAGE_B(t + 2, 0, par);
    HMFMA(1, 0);

    BARRIER();
    LOAD_A2v(sm + A_OFF(par), 1, 1);
    STAGE_B(t + 2, 1, par);
    STAGE_A(t + 2, 0, par);
    HMFMA(1, 1);
  }

  G1_EPILOGUE();
#undef A_OFF
#undef B_OFF
#undef STAGE_A
#undef STAGE_B
#undef BARRIER
}

// ---------------- GEMM1 first iter: also converts adj f32 -> adjb bf16 ----------------
// A reg-staged from f32 (t+1 prefetched into regs), B via GLDS; single-buffer 2-barrier.
// cb==0 blocks write adjb through (each element exactly once).
__global__ __launch_bounds__(512, 2)
void gemm1_first_kernel(const float* __restrict__ adjf, bf16* __restrict__ adjb,
                        const bf16* __restrict__ xbT, bf16* __restrict__ pbase) {
  __shared__ __align__(16) bf16 smA[16384];   // 256x64 swizzled, 32 KB
  __shared__ __align__(16) bf16 smB[16384];
  G1_DECODE();
  const int acol = (lane & 7) * 8;            // linear col (f32 src / adjb dst)

  f32x4 acc[8][4] = {};
  f32x4 pa[4][2];                             // prefetched A f32 (tile t+1)

#pragma unroll
  for (int c = 0; c < 4; ++c) {
    const float* src = adjf + (size_t)(prow0 + (wave * 4 + c) * 8 + srow) * NN + kb + acol;
    pa[c][0] = *(const f32x4*)src;
    pa[c][1] = *(const f32x4*)(src + 4);
  }

  for (int kt = 0; kt < 32; ++kt) {
    const int k0 = kb + kt * 64;
#pragma unroll
    for (int c = 0; c < 4; ++c) {
      int ch = wave * 4 + c;
      GLDS(xbT + (size_t)(bcol0 + ch * 8 + srow) * NN + k0 + scol, &smB[ch * 512]);
    }
#pragma unroll
    for (int c = 0; c < 4; ++c) {
      int ch = wave * 4 + c;
      int grow = prow0 + ch * 8 + srow;
      bf16x8 v;
#pragma unroll
      for (int e = 0; e < 4; ++e) { v[e] = (bf16)pa[c][0][e]; v[4 + e] = (bf16)pa[c][1][e]; }
      *(bf16x8*)&smA[ch * 512 + srow * 64 + scol] = v;   // swizzled slot (scol == swz*8)
      if (cb == 0) *(bf16x8*)&adjb[(size_t)grow * NN + k0 + acol] = v;
      if (kt < 31) {
        const float* src = adjf + (size_t)grow * NN + k0 + 64 + acol;
        pa[c][0] = *(const f32x4*)src;
        pa[c][1] = *(const f32x4*)(src + 4);
      }
    }
    __syncthreads();
    bf16x8 bv[2][4], afx[2][2];
    LOAD_Bv(smB, 0);
    LOAD_Bv(smB, 1);
#pragma unroll
    for (int h = 0; h < 2; ++h) {
      LOAD_A2v(smA, h, 0);
      HMFMA(h, 0);
      LOAD_A2v(smA, h, 1);
      HMFMA(h, 1);
    }
    __syncthreads();
  }

  G1_EPILOGUE();
}

// ---------------- GEMM2 (transposed): x_new^T = relu(Ws@x^T + Wn@(sum_s P_s)^T + b)^T ------
__global__ __launch_bounds__(1024, 4)
void gemm2_kernel(const bf16* __restrict__ wsb, const bf16* __restrict__ wnb,
                  bf16* __restrict__ xb, const bf16* __restrict__ pbase,
                  const float* __restrict__ bself, bf16* __restrict__ xbT) {
  __shared__ __align__(16) char smem[69632];
  bf16* lds_a = (bf16*)smem;             // W tile [512][64], 64 KB
  bf16* lds_b = (bf16*)(smem + 65536);   // x/Psum tile [32][64], 4 KB
  const int tid  = (int)threadIdx.x;
  const int lane = tid & 63;
  const int wave = tid >> 6;             // 0..15 -> d_out rows wave*32..+31
  const int n0 = (int)blockIdx.x * 32;
  const int fr = lane & 15, fq = lane >> 4;
  const int srow = lane >> 3;
  const int scol = ((lane & 7) ^ (srow & 7)) * 8;   // pre-swizzled source slot

  f32x4 acc[2][2] = {};

  for (int pr = 0; pr < 2; ++pr) {
    const bf16* __restrict__ A = pr ? wnb : wsb;    // [512][512]
    for (int kt = 0; kt < DD / 64; ++kt) {
      const int k0 = kt * 64;
#pragma unroll
      for (int c = 0; c < 4; ++c) {
        int chunk = wave * 4 + c;
        GLDS(A + (size_t)(chunk * 8 + srow) * DD + k0 + scol, &lds_a[chunk * 512]);
      }
      if (pr == 0) {
        if (wave < 4)
          GLDS(xb + (size_t)(n0 + wave * 8 + srow) * DD + k0 + scol, &lds_b[wave * 512]);
      } else if (tid < 256) {
        // fold: Psum = sum of 4 split-K partials, staged swizzled
        int node = tid >> 3, ks = tid & 7;
        const bf16* p0 = pbase + (size_t)(n0 + node) * DD + k0 + ks * 8;
        bf16x8 v0 = *(const bf16x8*)(p0);
        bf16x8 v1 = *(const bf16x8*)(p0 + PSZE);
        bf16x8 v2 = *(const bf16x8*)(p0 + 2 * PSZE);
        bf16x8 v3 = *(const bf16x8*)(p0 + 3 * PSZE);
        bf16x8 o;
#pragma unroll
        for (int j = 0; j < 8; ++j)
          o[j] = (bf16)((float)v0[j] + (float)v1[j] + (float)v2[j] + (float)v3[j]);
        *(bf16x8*)&lds_b[node * 64 + (ks ^ (node & 7)) * 8] = o;
      }
      __syncthreads();
      bf16x8 af[2][2], bv[2][2];
#pragma unroll
      for (int kk = 0; kk < 2; ++kk) {
#pragma unroll
        for (int m = 0; m < 2; ++m) {
          int rowl = wave * 32 + m * 16 + fr;
          int slot = (kk * 4 + fq) ^ (rowl & 7);
          af[kk][m] = *(const bf16x8*)&lds_a[rowl * 64 + slot * 8];
        }
#pragma unroll
        for (int n = 0; n < 2; ++n) {
          int rowl = n * 16 + fr;
          int slot = (kk * 4 + fq) ^ (rowl & 7);
          bv[kk][n] = *(const bf16x8*)&lds_b[rowl * 64 + slot * 8];
        }
      }
#pragma unroll
      for (int kk = 0; kk < 2; ++kk)
#pragma unroll
        for (int m = 0; m < 2; ++m)
#pragma unroll
          for (int n = 0; n < 2; ++n)
            acc[m][n] = __builtin_amdgcn_mfma_f32_16x16x32_bf16(af[kk][m], bv[kk][n], acc[m][n], 0, 0, 0);
      __syncthreads();
    }
  }
  // epilogue: C'[d][node]; d = wave*32+m*16+fq*4+r, node = n0 + n*16+fr
  bf16* lds_t = (bf16*)smem;  // [32 node][520 d]
#pragma unroll
  for (int m = 0; m < 2; ++m)
#pragma unroll
    for (int n = 0; n < 2; ++n)
#pragma unroll
      for (int r = 0; r < 4; ++r) {
        int d = wave * 32 + m * 16 + fq * 4 + r;
        int node = n * 16 + fr;
        float v = acc[m][n][r] + bself[d];
        v = v > 0.f ? v : 0.f;
        bf16 h = (bf16)v;
        xbT[(size_t)d * NN + n0 + node] = h;
        lds_t[node * 520 + d] = h;
      }
  __syncthreads();
  {
    int node = tid >> 5;
    int dc = (tid & 31) * 16;
    bf16x8 v0 = *(const bf16x8*)&lds_t[node * 520 + dc];
    bf16x8 v1 = *(const bf16x8*)&lds_t[node * 520 + dc + 8];
    *(bf16x8*)&xb[(size_t)(n0 + node) * DD + dc] = v0;
    *(bf16x8*)&xb[(size_t)(n0 + node) * DD + dc + 8] = v1;
  }
}

// ---------------- pooling + head ----------------

__global__ __launch_bounds__(256) void pool_kernel(
    const bf16* __restrict__ xb, float* __restrict__ pooled) {
  const int t = (int)threadIdx.x;
  const int r0 = (int)blockIdx.x * 32;
  float s0 = 0.f, s1 = 0.f;
  for (int r = 0; r < 32; ++r) {
    s0 += (float)xb[(size_t)(r0 + r) * DD + t];
    s1 += (float)xb[(size_t)(r0 + r) * DD + t + 256];
  }
  atomicAdd(&pooled[t], s0);
  atomicAdd(&pooled[t + 256], s1);
}

__global__ __launch_bounds__(64) void final_kernel(
    const float* __restrict__ pooled, const float* __restrict__ features,
    const float* __restrict__ wfc, const float* __restrict__ bfc,
    float* __restrict__ out) {
  const int t = (int)threadIdx.x;
  float s = 0.f;
  for (int i = t; i < DD + 64; i += 64) {
    float v = (i < DD) ? pooled[i] * (1.0f / (float)NN) : features[i - DD];
    s += v * wfc[i];
  }
#pragma unroll
  for (int off = 32; off > 0; off >>= 1) s += __shfl_down(s, off);
  if (t == 0) {
    float z = s + bfc[0];
    out[0] = 1.0f / (1.0f + expf(-z));
  }
}

// ---------------- launch ----------------

extern "C" void kernel_launch(void* const* d_in, const int* in_sizes, int n_in,
                              void* d_out, int out_size, void* d_ws, size_t ws_size,
                              hipStream_t stream) {
  const float* labels   = (const float*)d_in[0];
  const float* adj      = (const float*)d_in[1];
  const float* features = (const float*)d_in[2];
  const float* W_self   = (const float*)d_in[3];
  const float* b_self   = (const float*)d_in[4];
  const float* W_neigh  = (const float*)d_in[5];
  const float* W_fc     = (const float*)d_in[6];
  const float* b_fc     = (const float*)d_in[7];
  float* out = (float*)d_out;

  char* ws = (char*)d_ws;   // ws_size = 1 GiB (observed); layout needs ~185.6 MB
  bf16*  xb    = (bf16*)(ws);
  bf16*  xbT   = (bf16*)(ws + PSZB);
  bf16*  pbase = (bf16*)(ws + 2 * PSZB);
  char*  after_p = ws + (size_t)(2 + NS) * PSZB;
  bf16*  wsb    = (bf16*)(after_p);
  bf16*  wnb    = (bf16*)(after_p + 524288);
  float* pooled = (float*)(after_p + 1048576);
  bf16*  adjb   = (bf16*)(after_p + 1048576 + 4096);

  convert_w_kernel<<<2 * DD * DD / 8 / 256, 256, 0, stream>>>(W_self, W_neigh, wsb, wnb);
  convert_x_kernel<<<dim3(NN / 64, DD / 64), 256, 0, stream>>>(labels, xb, xbT);

  for (int it = 0; it < 4; ++it) {
    if (it == 0)
      gemm1_first_kernel<<<256, 512, 0, stream>>>(adj, adjb, xbT, pbase);
    else
      gemm1_kernel<<<256, 512, 0, stream>>>(adjb, xbT, pbase);
    gemm2_kernel<<<NN / 32, 1024, 0, stream>>>(wsb, wnb, xb, pbase, b_self, xbT);
  }

  hipMemsetAsync(pooled, 0, DD * sizeof(float), stream);
  pool_kernel<<<NN / 32, 256, 0, stream>>>(xb, pooled);
  final_kernel<<<1, 64, 0, stream>>>(pooled, features, W_fc, b_fc, out);
}

// Round 6
// 462.687 us; speedup vs baseline: 1.0131x; 1.0131x over previous
//
#include <hip/hip_runtime.h>

typedef __bf16 bf16;
typedef bf16 bf16x8 __attribute__((ext_vector_type(8)));
typedef bf16 bf16x4 __attribute__((ext_vector_type(4)));
typedef float f32x4 __attribute__((ext_vector_type(4)));
typedef float f32x16 __attribute__((ext_vector_type(16)));

constexpr int NN = 8192;   // nodes
constexpr int DD = 512;    // gnn dim
constexpr size_t PSZB = (size_t)NN * DD * 2;   // 8 MB, one bf16 [NN][DD] buffer
constexpr size_t PSZE = (size_t)NN * DD;       // elements
constexpr int NS = 4;                          // split-K factor

static __device__ inline bf16x8 cvt8(const float* __restrict__ p) {
  f32x4 a = *(const f32x4*)p;
  f32x4 b = *(const f32x4*)(p + 4);
  bf16x8 r;
  r[0] = (bf16)a[0]; r[1] = (bf16)a[1]; r[2] = (bf16)a[2]; r[3] = (bf16)a[3];
  r[4] = (bf16)b[0]; r[5] = (bf16)b[1]; r[6] = (bf16)b[2]; r[7] = (bf16)b[3];
  return r;
}

// async global->LDS, 16B per lane, dest = wave-uniform base + lane*16
#define GLDS(g, l) __builtin_amdgcn_global_load_lds( \
    (const __attribute__((address_space(1))) unsigned int*)(const void*)(g), \
    (__attribute__((address_space(3))) unsigned int*)(void*)(l), 16, 0, 0)

// ---------------- converts ----------------

__global__ __launch_bounds__(256) void convert_w_kernel(
    const float* __restrict__ a, const float* __restrict__ b,
    bf16* __restrict__ ao, bf16* __restrict__ bo) {
  int i8 = ((int)blockIdx.x * 256 + (int)threadIdx.x) * 8;
  if (i8 < DD * DD) {
    *(bf16x8*)&ao[i8] = cvt8(a + i8);
  } else {
    int j = i8 - DD * DD;
    *(bf16x8*)&bo[j] = cvt8(b + j);
  }
}

__global__ __launch_bounds__(256) void convert_adj_kernel(
    const float* __restrict__ a, bf16* __restrict__ o) {
  size_t i8 = ((size_t)blockIdx.x * 256 + threadIdx.x) * 8;
  *(bf16x8*)&o[i8] = cvt8(a + i8);
}

// labels f32 [NN][DD] -> xb bf16 [NN][DD] and xbT bf16 [DD][NN] (64x64 LDS tiles)
__global__ __launch_bounds__(256) void convert_x_kernel(
    const float* __restrict__ src, bf16* __restrict__ xb, bf16* __restrict__ xbT) {
  __shared__ __align__(16) float tile[64][68];
  const int tid = (int)threadIdx.x;
  const int r0 = (int)blockIdx.x * 64;
  const int c0 = (int)blockIdx.y * 64;
#pragma unroll
  for (int p = 0; p < 4; ++p) {
    int row = p * 16 + (tid >> 4);
    int col = (tid & 15) * 4;
    *(f32x4*)&tile[row][col] = *(const f32x4*)&src[(size_t)(r0 + row) * DD + c0 + col];
  }
  __syncthreads();
#pragma unroll
  for (int p = 0; p < 4; ++p) {
    int row = p * 16 + (tid >> 4);
    int col = (tid & 15) * 4;
    f32x4 v = *(const f32x4*)&tile[row][col];
    bf16x4 o;
    o[0] = (bf16)v[0]; o[1] = (bf16)v[1]; o[2] = (bf16)v[2]; o[3] = (bf16)v[3];
    *(bf16x4*)&xb[(size_t)(r0 + row) * DD + c0 + col] = o;
  }
  {
    int c = tid >> 2;
    int rp = (tid & 3) * 16;
    bf16x8 o0, o1;
#pragma unroll
    for (int j = 0; j < 8; ++j) o0[j] = (bf16)tile[rp + j][c];
#pragma unroll
    for (int j = 0; j < 8; ++j) o1[j] = (bf16)tile[rp + 8 + j][c];
    *(bf16x8*)&xbT[(size_t)(c0 + c) * NN + r0 + rp] = o0;
    *(bf16x8*)&xbT[(size_t)(c0 + c) * NN + r0 + rp + 8] = o1;
  }
}

// ---------------- GEMM1: P_s = bf16( adjb[:,ks:ke] @ x[ks:ke,:] ) ----------------
// BM=BN=256, BK=64, 512 thr (8 waves 2Mx4N), split-K=4, mfma 32x32x16.
// XCD remap: both cb-blocks of a (p,s) A-slice on one XCD; B-slice L2-resident.
// 4 phases/K-tile, dbuf, counted vmcnt(8), T2 swizzle (verified 0 conflicts R5).

__device__ __forceinline__ void stage_half(const bf16* __restrict__ g, int grow0, int k0,
                                           bf16* smbase, int wave, int lane) {
#pragma unroll
  for (int i = 0; i < 2; ++i) {
    int c = wave * 2 + i;                                    // chunk 0..15, 1 KB each
    int row = grow0 + c * 8 + (lane >> 3);
    int col = k0 + (((lane & 7) ^ ((lane >> 3) & 7)) << 3);  // pre-swizzled source slot
    GLDS(g + (size_t)row * NN + col, smbase + c * 512);
  }
}

__global__ __launch_bounds__(512, 2)
void gemm1_kernel(const bf16* __restrict__ adjb, const bf16* __restrict__ xbT,
                  bf16* __restrict__ pbase) {
  __shared__ __align__(16) bf16 sm[65536];   // [par][A 16384 | B 16384], 128 KiB
  const int bid  = (int)blockIdx.x;
  const int xcd  = bid & 7, ii = bid >> 3;
  const int cb   = ii & 1;
  const int jj_  = xcd + 8 * (ii >> 1);
  const int p    = jj_ >> 2;
  const int s    = jj_ & 3;
  const int prow0 = p * 256;
  const int bcol0 = cb * 256;
  const int kb    = s * 2048;
  bf16* __restrict__ P = pbase + (size_t)s * PSZE;

  const int tid  = (int)threadIdx.x;
  const int lane = tid & 63;
  const int wave = tid >> 6;            // 0..7
  const int wr   = wave >> 2;           // 0..1
  const int wc   = wave & 3;            // 0..3
  const int l31  = lane & 31;
  const int kh   = lane >> 5;           // k-half selector

  f32x16 acc[4][2] = {};                // m (4x32 rows, h-first) x n (2x32 cols)

#define A_OFF(par) ((par) * 32768)
#define B_OFF(par) ((par) * 32768 + 16384)
#define STAGE_A(tile, half, par) \
  stage_half(adjb, prow0 + (half) * 128, kb + ((tile) & 31) * 64, \
             sm + A_OFF(par) + (half) * 8192, wave, lane)
#define STAGE_B(tile, half, par) \
  stage_half(xbT, bcol0 + (half) * 128, kb + ((tile) & 31) * 64, \
             sm + B_OFF(par) + (half) * 8192, wave, lane)
#define BARRIER() __builtin_amdgcn_s_barrier(); __builtin_amdgcn_sched_barrier(0)

  // prologue (14 loads): B(0), Ah0(0), Ah1(0), B(1), Ah0(1)
  STAGE_B(0, 0, 0); STAGE_B(0, 1, 0); STAGE_A(0, 0, 0); STAGE_A(0, 1, 0);
  STAGE_B(1, 0, 1); STAGE_B(1, 1, 1); STAGE_A(1, 0, 1);

  bf16x8 bv[4][2], af[4];

  // m-chunk -> LDS rows: rowl = m*64 + wr*32 + l31  (m 0,1 -> Ah0; m 2,3 -> Ah1)
#define LOAD_B32(par)                                                      \
  _Pragma("unroll") for (int kk = 0; kk < 4; ++kk)                         \
  _Pragma("unroll") for (int n = 0; n < 2; ++n) {                          \
    int rowl = wc * 64 + n * 32 + l31;                                     \
    int slot = (kk * 2 + kh) ^ (rowl & 7);                                 \
    bv[kk][n] = *(const bf16x8*)&sm[B_OFF(par) + rowl * 64 + slot * 8];    \
  }
#define LOAD_A32(m, par)                                                   \
  _Pragma("unroll") for (int kk = 0; kk < 4; ++kk) {                       \
    int rowl = (m) * 64 + wr * 32 + l31;                                   \
    int slot = (kk * 2 + kh) ^ (rowl & 7);                                 \
    af[kk] = *(const bf16x8*)&sm[A_OFF(par) + rowl * 64 + slot * 8];       \
  }
#define MMFMA(m)                                                           \
  __builtin_amdgcn_s_setprio(1);                                           \
  _Pragma("unroll") for (int kk = 0; kk < 4; ++kk)                         \
  _Pragma("unroll") for (int n = 0; n < 2; ++n)                            \
    acc[m][n] = __builtin_amdgcn_mfma_f32_32x32x16_bf16(                   \
        af[kk], bv[kk][n], acc[m][n], 0, 0, 0);                            \
  __builtin_amdgcn_s_setprio(0);

  // issue pattern per phase: P1:2 (Ah1 t+1), P2:0, P3:2 (Bh0 t+2), P4:4 (Bh1,Ah0 t+2)
  // P1 needs Ah0(t): 8 newer loads in flight -> vmcnt(8); P3 needs Ah1(t): vmcnt(8)
  int par = 0;
  for (int t = 0; t < 32; ++t, par ^= 1) {
    asm volatile("s_waitcnt vmcnt(8)" ::: "memory");
    BARRIER();
    LOAD_B32(par);
    LOAD_A32(0, par);
    STAGE_A(t + 1, 1, par ^ 1);
    MMFMA(0);

    BARRIER();
    LOAD_A32(1, par);
    MMFMA(1);

    asm volatile("s_waitcnt vmcnt(8)" ::: "memory");
    BARRIER();
    LOAD_A32(2, par);
    STAGE_B(t + 2, 0, par);
    MMFMA(2);

    BARRIER();
    LOAD_A32(3, par);
    STAGE_B(t + 2, 1, par);
    STAGE_A(t + 2, 0, par);
    MMFMA(3);
  }

  // epilogue: 32x32 C/D layout col=lane&31, row=(r&3)+8*(r>>2)+4*(lane>>5)
#pragma unroll
  for (int m = 0; m < 4; ++m)
#pragma unroll
    for (int n = 0; n < 2; ++n)
#pragma unroll
      for (int r = 0; r < 16; ++r) {
        int row = prow0 + m * 64 + wr * 32 + (r & 3) + 8 * (r >> 2) + 4 * kh;
        int col = bcol0 + wc * 64 + n * 32 + l31;
        P[(size_t)row * DD + col] = (bf16)acc[m][n][r];
      }
#undef A_OFF
#undef B_OFF
#undef STAGE_A
#undef STAGE_B
#undef LOAD_B32
#undef LOAD_A32
#undef MMFMA
#undef BARRIER
}

// ---------------- GEMM2 (transposed): x_new^T = relu(Ws@x^T + Wn@(sum_s P_s)^T + b)^T ------
__global__ __launch_bounds__(1024, 4)
void gemm2_kernel(const bf16* __restrict__ wsb, const bf16* __restrict__ wnb,
                  bf16* __restrict__ xb, const bf16* __restrict__ pbase,
                  const float* __restrict__ bself, bf16* __restrict__ xbT) {
  __shared__ __align__(16) char smem[69632];
  bf16* lds_a = (bf16*)smem;             // W tile [512][64], 64 KB
  bf16* lds_b = (bf16*)(smem + 65536);   // x/Psum tile [32][64], 4 KB
  const int tid  = (int)threadIdx.x;
  const int lane = tid & 63;
  const int wave = tid >> 6;             // 0..15 -> d_out rows wave*32..+31
  const int n0 = (int)blockIdx.x * 32;
  const int fr = lane & 15, fq = lane >> 4;
  const int srow = lane >> 3;
  const int scol = ((lane & 7) ^ (srow & 7)) * 8;   // pre-swizzled source slot

  f32x4 acc[2][2] = {};

  for (int pr = 0; pr < 2; ++pr) {
    const bf16* __restrict__ A = pr ? wnb : wsb;    // [512][512]
    for (int kt = 0; kt < DD / 64; ++kt) {
      const int k0 = kt * 64;
#pragma unroll
      for (int c = 0; c < 4; ++c) {
        int chunk = wave * 4 + c;
        GLDS(A + (size_t)(chunk * 8 + srow) * DD + k0 + scol, &lds_a[chunk * 512]);
      }
      if (pr == 0) {
        if (wave < 4)
          GLDS(xb + (size_t)(n0 + wave * 8 + srow) * DD + k0 + scol, &lds_b[wave * 512]);
      } else if (tid < 256) {
        // fold: Psum = sum of 4 split-K partials, staged swizzled
        int node = tid >> 3, ks = tid & 7;
        const bf16* p0 = pbase + (size_t)(n0 + node) * DD + k0 + ks * 8;
        bf16x8 v0 = *(const bf16x8*)(p0);
        bf16x8 v1 = *(const bf16x8*)(p0 + PSZE);
        bf16x8 v2 = *(const bf16x8*)(p0 + 2 * PSZE);
        bf16x8 v3 = *(const bf16x8*)(p0 + 3 * PSZE);
        bf16x8 o;
#pragma unroll
        for (int j = 0; j < 8; ++j)
          o[j] = (bf16)((float)v0[j] + (float)v1[j] + (float)v2[j] + (float)v3[j]);
        *(bf16x8*)&lds_b[node * 64 + (ks ^ (node & 7)) * 8] = o;
      }
      __syncthreads();
      bf16x8 af[2][2], bv[2][2];
#pragma unroll
      for (int kk = 0; kk < 2; ++kk) {
#pragma unroll
        for (int m = 0; m < 2; ++m) {
          int rowl = wave * 32 + m * 16 + fr;
          int slot = (kk * 4 + fq) ^ (rowl & 7);
          af[kk][m] = *(const bf16x8*)&lds_a[rowl * 64 + slot * 8];
        }
#pragma unroll
        for (int n = 0; n < 2; ++n) {
          int rowl = n * 16 + fr;
          int slot = (kk * 4 + fq) ^ (rowl & 7);
          bv[kk][n] = *(const bf16x8*)&lds_b[rowl * 64 + slot * 8];
        }
      }
#pragma unroll
      for (int kk = 0; kk < 2; ++kk)
#pragma unroll
        for (int m = 0; m < 2; ++m)
#pragma unroll
          for (int n = 0; n < 2; ++n)
            acc[m][n] = __builtin_amdgcn_mfma_f32_16x16x32_bf16(af[kk][m], bv[kk][n], acc[m][n], 0, 0, 0);
      __syncthreads();
    }
  }
  // epilogue: C'[d][node]; d = wave*32+m*16+fq*4+r, node = n0 + n*16+fr
  bf16* lds_t = (bf16*)smem;  // [32 node][520 d]
#pragma unroll
  for (int m = 0; m < 2; ++m)
#pragma unroll
    for (int n = 0; n < 2; ++n)
#pragma unroll
      for (int r = 0; r < 4; ++r) {
        int d = wave * 32 + m * 16 + fq * 4 + r;
        int node = n * 16 + fr;
        float v = acc[m][n][r] + bself[d];
        v = v > 0.f ? v : 0.f;
        bf16 h = (bf16)v;
        xbT[(size_t)d * NN + n0 + node] = h;
        lds_t[node * 520 + d] = h;
      }
  __syncthreads();
  {
    int node = tid >> 5;
    int dc = (tid & 31) * 16;
    bf16x8 v0 = *(const bf16x8*)&lds_t[node * 520 + dc];
    bf16x8 v1 = *(const bf16x8*)&lds_t[node * 520 + dc + 8];
    *(bf16x8*)&xb[(size_t)(n0 + node) * DD + dc] = v0;
    *(bf16x8*)&xb[(size_t)(n0 + node) * DD + dc + 8] = v1;
  }
}

// ---------------- pooling + head ----------------

__global__ __launch_bounds__(256) void pool_kernel(
    const bf16* __restrict__ xb, float* __restrict__ pooled) {
  const int t = (int)threadIdx.x;
  const int r0 = (int)blockIdx.x * 32;
  float s0 = 0.f, s1 = 0.f;
  for (int r = 0; r < 32; ++r) {
    s0 += (float)xb[(size_t)(r0 + r) * DD + t];
    s1 += (float)xb[(size_t)(r0 + r) * DD + t + 256];
  }
  atomicAdd(&pooled[t], s0);
  atomicAdd(&pooled[t + 256], s1);
}

__global__ __launch_bounds__(64) void final_kernel(
    const float* __restrict__ pooled, const float* __restrict__ features,
    const float* __restrict__ wfc, const float* __restrict__ bfc,
    float* __restrict__ out) {
  const int t = (int)threadIdx.x;
  float s = 0.f;
  for (int i = t; i < DD + 64; i += 64) {
    float v = (i < DD) ? pooled[i] * (1.0f / (float)NN) : features[i - DD];
    s += v * wfc[i];
  }
#pragma unroll
  for (int off = 32; off > 0; off >>= 1) s += __shfl_down(s, off);
  if (t == 0) {
    float z = s + bfc[0];
    out[0] = 1.0f / (1.0f + expf(-z));
  }
}

// ---------------- launch ----------------

extern "C" void kernel_launch(void* const* d_in, const int* in_sizes, int n_in,
                              void* d_out, int out_size, void* d_ws, size_t ws_size,
                              hipStream_t stream) {
  const float* labels   = (const float*)d_in[0];
  const float* adj      = (const float*)d_in[1];
  const float* features = (const float*)d_in[2];
  const float* W_self   = (const float*)d_in[3];
  const float* b_self   = (const float*)d_in[4];
  const float* W_neigh  = (const float*)d_in[5];
  const float* W_fc     = (const float*)d_in[6];
  const float* b_fc     = (const float*)d_in[7];
  float* out = (float*)d_out;

  char* ws = (char*)d_ws;   // ws_size = 1 GiB (observed); layout needs ~185.6 MB
  bf16*  xb    = (bf16*)(ws);
  bf16*  xbT   = (bf16*)(ws + PSZB);
  bf16*  pbase = (bf16*)(ws + 2 * PSZB);
  char*  after_p = ws + (size_t)(2 + NS) * PSZB;
  bf16*  wsb    = (bf16*)(after_p);
  bf16*  wnb    = (bf16*)(after_p + 524288);
  float* pooled = (float*)(after_p + 1048576);
  bf16*  adjb   = (bf16*)(after_p + 1048576 + 4096);

  convert_w_kernel<<<2 * DD * DD / 8 / 256, 256, 0, stream>>>(W_self, W_neigh, wsb, wnb);
  convert_adj_kernel<<<(int)((size_t)NN * NN / 8 / 256), 256, 0, stream>>>(adj, adjb);
  convert_x_kernel<<<dim3(NN / 64, DD / 64), 256, 0, stream>>>(labels, xb, xbT);

  for (int it = 0; it < 4; ++it) {
    gemm1_kernel<<<256, 512, 0, stream>>>(adjb, xbT, pbase);
    gemm2_kernel<<<NN / 32, 1024, 0, stream>>>(wsb, wnb, xb, pbase, b_self, xbT);
  }

  hipMemsetAsync(pooled, 0, DD * sizeof(float), stream);
  pool_kernel<<<NN / 32, 256, 0, stream>>>(xb, pooled);
  final_kernel<<<1, 64, 0, stream>>>(pooled, features, W_fc, b_fc, out);
}

// Round 7
// 449.723 us; speedup vs baseline: 1.0423x; 1.0288x over previous
//
#include <hip/hip_runtime.h>

typedef __bf16 bf16;
typedef bf16 bf16x8 __attribute__((ext_vector_type(8)));
typedef bf16 bf16x4 __attribute__((ext_vector_type(4)));
typedef float f32x4 __attribute__((ext_vector_type(4)));

constexpr int NN = 8192;   // nodes
constexpr int DD = 512;    // gnn dim
constexpr size_t PSZB = (size_t)NN * DD * 2;   // 8 MB, one bf16 [NN][DD] buffer
constexpr size_t PSZE = (size_t)NN * DD;       // elements
constexpr int NS = 4;                          // split-K factor

static __device__ inline bf16x8 cvt8(const float* __restrict__ p) {
  f32x4 a = *(const f32x4*)p;
  f32x4 b = *(const f32x4*)(p + 4);
  bf16x8 r;
  r[0] = (bf16)a[0]; r[1] = (bf16)a[1]; r[2] = (bf16)a[2]; r[3] = (bf16)a[3];
  r[4] = (bf16)b[0]; r[5] = (bf16)b[1]; r[6] = (bf16)b[2]; r[7] = (bf16)b[3];
  return r;
}

// async global->LDS, 16B per lane, dest = wave-uniform base + lane*16
#define GLDS(g, l) __builtin_amdgcn_global_load_lds( \
    (const __attribute__((address_space(1))) unsigned int*)(const void*)(g), \
    (__attribute__((address_space(3))) unsigned int*)(void*)(l), 16, 0, 0)

// ---------------- converts ----------------

__global__ __launch_bounds__(256) void convert_w_kernel(
    const float* __restrict__ a, const float* __restrict__ b,
    bf16* __restrict__ ao, bf16* __restrict__ bo) {
  int i8 = ((int)blockIdx.x * 256 + (int)threadIdx.x) * 8;
  if (i8 < DD * DD) {
    *(bf16x8*)&ao[i8] = cvt8(a + i8);
  } else {
    int j = i8 - DD * DD;
    *(bf16x8*)&bo[j] = cvt8(b + j);
  }
}

__global__ __launch_bounds__(256) void convert_adj_kernel(
    const float* __restrict__ a, bf16* __restrict__ o) {
  size_t i8 = ((size_t)blockIdx.x * 256 + threadIdx.x) * 8;
  *(bf16x8*)&o[i8] = cvt8(a + i8);
}

// labels f32 [NN][DD] -> xb bf16 [NN][DD] and xbT bf16 [DD][NN] (64x64 LDS tiles)
__global__ __launch_bounds__(256) void convert_x_kernel(
    const float* __restrict__ src, bf16* __restrict__ xb, bf16* __restrict__ xbT) {
  __shared__ __align__(16) float tile[64][68];
  const int tid = (int)threadIdx.x;
  const int r0 = (int)blockIdx.x * 64;
  const int c0 = (int)blockIdx.y * 64;
#pragma unroll
  for (int p = 0; p < 4; ++p) {
    int row = p * 16 + (tid >> 4);
    int col = (tid & 15) * 4;
    *(f32x4*)&tile[row][col] = *(const f32x4*)&src[(size_t)(r0 + row) * DD + c0 + col];
  }
  __syncthreads();
#pragma unroll
  for (int p = 0; p < 4; ++p) {
    int row = p * 16 + (tid >> 4);
    int col = (tid & 15) * 4;
    f32x4 v = *(const f32x4*)&tile[row][col];
    bf16x4 o;
    o[0] = (bf16)v[0]; o[1] = (bf16)v[1]; o[2] = (bf16)v[2]; o[3] = (bf16)v[3];
    *(bf16x4*)&xb[(size_t)(r0 + row) * DD + c0 + col] = o;
  }
  {
    int c = tid >> 2;
    int rp = (tid & 3) * 16;
    bf16x8 o0, o1;
#pragma unroll
    for (int j = 0; j < 8; ++j) o0[j] = (bf16)tile[rp + j][c];
#pragma unroll
    for (int j = 0; j < 8; ++j) o1[j] = (bf16)tile[rp + 8 + j][c];
    *(bf16x8*)&xbT[(size_t)(c0 + c) * NN + r0 + rp] = o0;
    *(bf16x8*)&xbT[(size_t)(c0 + c) * NN + r0 + rp + 8] = o1;
  }
}

// ---------------- GEMM1: P_s = bf16( adjb[:,ks:ke] @ x[ks:ke,:] ) ----------------
// BM=BN=256, BK=64, 512 thr (8 waves 2Mx4N), split-K=4, mfma 16x16x32.
// XCD remap: both cb-blocks of a (p,s) A-slice on one XCD.
// 2 merged phases per K-tile (2 barriers, 1 vmcnt(6)), dbuf, T2 swizzle.

__device__ __forceinline__ void stage_half(const bf16* __restrict__ g, int grow0, int k0,
                                           bf16* smbase, int wave, int lane) {
#pragma unroll
  for (int i = 0; i < 2; ++i) {
    int c = wave * 2 + i;                                    // chunk 0..15, 1 KB each
    int row = grow0 + c * 8 + (lane >> 3);
    int col = k0 + (((lane & 7) ^ ((lane >> 3) & 7)) << 3);  // pre-swizzled source slot
    GLDS(g + (size_t)row * NN + col, smbase + c * 512);
  }
}

__global__ __launch_bounds__(512, 2)
void gemm1_kernel(const bf16* __restrict__ adjb, const bf16* __restrict__ xbT,
                  bf16* __restrict__ pbase) {
  __shared__ __align__(16) bf16 sm[65536];   // [par][A 16384 | B 16384], 128 KiB
  const int bid  = (int)blockIdx.x;
  const int xcd  = bid & 7, ii = bid >> 3;
  const int cb   = ii & 1;
  const int jj_  = xcd + 8 * (ii >> 1);
  const int p    = jj_ >> 2;
  const int s    = jj_ & 3;
  const int prow0 = p * 256;
  const int bcol0 = cb * 256;
  const int kb    = s * 2048;
  bf16* __restrict__ P = pbase + (size_t)s * PSZE;

  const int tid  = (int)threadIdx.x;
  const int lane = tid & 63;
  const int wave = tid >> 6;            // 0..7
  const int wr   = wave >> 2;           // 0..1
  const int wc   = wave & 3;            // 0..3
  const int fr   = lane & 15, fq = lane >> 4;

  f32x4 acc[8][4] = {};

#define A_OFF(par) ((par) * 32768)
#define B_OFF(par) ((par) * 32768 + 16384)
#define STAGE_A(tile, half, par) \
  stage_half(adjb, prow0 + (half) * 128, kb + ((tile) & 31) * 64, \
             sm + A_OFF(par) + (half) * 8192, wave, lane)
#define STAGE_B(tile, half, par) \
  stage_half(xbT, bcol0 + (half) * 128, kb + ((tile) & 31) * 64, \
             sm + B_OFF(par) + (half) * 8192, wave, lane)
#define BARRIER() __builtin_amdgcn_s_barrier(); __builtin_amdgcn_sched_barrier(0)

  // prologue (14 insts): B(0), Ah0(0), Ah1(0), B(1), Ah0(1)
  STAGE_B(0, 0, 0); STAGE_B(0, 1, 0); STAGE_A(0, 0, 0); STAGE_A(0, 1, 0);
  STAGE_B(1, 0, 1); STAGE_B(1, 1, 1); STAGE_A(1, 0, 1);

  bf16x8 bv[2][4], af[2][2];

#define LOAD_B(par)                                                        \
  _Pragma("unroll") for (int kk = 0; kk < 2; ++kk)                         \
  _Pragma("unroll") for (int n = 0; n < 4; ++n) {                          \
    int rowl = wc * 64 + n * 16 + fr;                                      \
    int slot = (kk * 4 + fq) ^ (rowl & 7);                                 \
    bv[kk][n] = *(const bf16x8*)&sm[B_OFF(par) + rowl * 64 + slot * 8];    \
  }
#define LOAD_A(q, par)                                                     \
  _Pragma("unroll") for (int kk = 0; kk < 2; ++kk)                         \
  _Pragma("unroll") for (int j = 0; j < 2; ++j) {                          \
    int rowl = (q) * 64 + wr * 32 + j * 16 + fr;                           \
    int slot = (kk * 4 + fq) ^ (rowl & 7);                                 \
    af[kk][j] = *(const bf16x8*)&sm[A_OFF(par) + rowl * 64 + slot * 8];    \
  }
#define QMFMA(q)                                                           \
  __builtin_amdgcn_s_setprio(1);                                           \
  _Pragma("unroll") for (int kk = 0; kk < 2; ++kk)                         \
  _Pragma("unroll") for (int j = 0; j < 2; ++j)                            \
  _Pragma("unroll") for (int n = 0; n < 4; ++n)                            \
    acc[2 * (q) + j][n] = __builtin_amdgcn_mfma_f32_16x16x32_bf16(         \
        af[kk][j], bv[kk][n], acc[2 * (q) + j][n], 0, 0, 0);               \
  __builtin_amdgcn_s_setprio(0);

  // 2 merged phases per tile. Issue: phase A = 2 (Ah1 t+1 -> par^1),
  // phase B = 6 (Bh0,Bh1,Ah0 t+2 -> par). Single wait: at phase A,
  // Ah1(t) has exactly 6 newer insts in flight -> vmcnt(6) (prologue exact).
  // Every stage targets a region whose readers are one barrier behind.
  int par = 0;
  for (int t = 0; t < 32; ++t, par ^= 1) {
    // ---- phase A: B(all) + A q0,q1 ----
    asm volatile("s_waitcnt vmcnt(6)" ::: "memory");
    BARRIER();
    LOAD_B(par);
    LOAD_A(0, par);
    STAGE_A(t + 1, 1, par ^ 1);
    QMFMA(0);
    LOAD_A(1, par);
    QMFMA(1);

    // ---- phase B: A q2,q3 ----
    BARRIER();
    LOAD_A(2, par);
    STAGE_B(t + 2, 0, par);
    STAGE_B(t + 2, 1, par);
    STAGE_A(t + 2, 0, par);
    QMFMA(2);
    LOAD_A(3, par);
    QMFMA(3);
  }

  // epilogue: C/D frag layout col=lane&15, row=(lane>>4)*4+reg
#pragma unroll
  for (int m = 0; m < 8; ++m)
#pragma unroll
    for (int n = 0; n < 4; ++n)
#pragma unroll
      for (int r = 0; r < 4; ++r) {
        int row = prow0 + (m >> 1) * 64 + wr * 32 + (m & 1) * 16 + fq * 4 + r;
        int col = bcol0 + wc * 64 + n * 16 + fr;
        P[(size_t)row * DD + col] = (bf16)acc[m][n][r];
      }
#undef A_OFF
#undef B_OFF
#undef STAGE_A
#undef STAGE_B
#undef LOAD_B
#undef LOAD_A
#undef QMFMA
#undef BARRIER
}

// ---------------- GEMM2 (transposed): x_new^T = relu(Ws@x^T + Wn@(sum_s P_s)^T + b)^T ------
__global__ __launch_bounds__(1024, 4)
void gemm2_kernel(const bf16* __restrict__ wsb, const bf16* __restrict__ wnb,
                  bf16* __restrict__ xb, const bf16* __restrict__ pbase,
                  const float* __restrict__ bself, bf16* __restrict__ xbT) {
  __shared__ __align__(16) char smem[69632];
  bf16* lds_a = (bf16*)smem;             // W tile [512][64], 64 KB
  bf16* lds_b = (bf16*)(smem + 65536);   // x/Psum tile [32][64], 4 KB
  const int tid  = (int)threadIdx.x;
  const int lane = tid & 63;
  const int wave = tid >> 6;             // 0..15 -> d_out rows wave*32..+31
  const int n0 = (int)blockIdx.x * 32;
  const int fr = lane & 15, fq = lane >> 4;
  const int srow = lane >> 3;
  const int scol = ((lane & 7) ^ (srow & 7)) * 8;   // pre-swizzled source slot

  f32x4 acc[2][2] = {};

  for (int pr = 0; pr < 2; ++pr) {
    const bf16* __restrict__ A = pr ? wnb : wsb;    // [512][512]
    for (int kt = 0; kt < DD / 64; ++kt) {
      const int k0 = kt * 64;
#pragma unroll
      for (int c = 0; c < 4; ++c) {
        int chunk = wave * 4 + c;
        GLDS(A + (size_t)(chunk * 8 + srow) * DD + k0 + scol, &lds_a[chunk * 512]);
      }
      if (pr == 0) {
        if (wave < 4)
          GLDS(xb + (size_t)(n0 + wave * 8 + srow) * DD + k0 + scol, &lds_b[wave * 512]);
      } else if (tid < 256) {
        // fold: Psum = sum of 4 split-K partials, staged swizzled
        int node = tid >> 3, ks = tid & 7;
        const bf16* p0 = pbase + (size_t)(n0 + node) * DD + k0 + ks * 8;
        bf16x8 v0 = *(const bf16x8*)(p0);
        bf16x8 v1 = *(const bf16x8*)(p0 + PSZE);
        bf16x8 v2 = *(const bf16x8*)(p0 + 2 * PSZE);
        bf16x8 v3 = *(const bf16x8*)(p0 + 3 * PSZE);
        bf16x8 o;
#pragma unroll
        for (int j = 0; j < 8; ++j)
          o[j] = (bf16)((float)v0[j] + (float)v1[j] + (float)v2[j] + (float)v3[j]);
        *(bf16x8*)&lds_b[node * 64 + (ks ^ (node & 7)) * 8] = o;
      }
      __syncthreads();
      bf16x8 af[2][2], bv[2][2];
#pragma unroll
      for (int kk = 0; kk < 2; ++kk) {
#pragma unroll
        for (int m = 0; m < 2; ++m) {
          int rowl = wave * 32 + m * 16 + fr;
          int slot = (kk * 4 + fq) ^ (rowl & 7);
          af[kk][m] = *(const bf16x8*)&lds_a[rowl * 64 + slot * 8];
        }
#pragma unroll
        for (int n = 0; n < 2; ++n) {
          int rowl = n * 16 + fr;
          int slot = (kk * 4 + fq) ^ (rowl & 7);
          bv[kk][n] = *(const bf16x8*)&lds_b[rowl * 64 + slot * 8];
        }
      }
#pragma unroll
      for (int kk = 0; kk < 2; ++kk)
#pragma unroll
        for (int m = 0; m < 2; ++m)
#pragma unroll
          for (int n = 0; n < 2; ++n)
            acc[m][n] = __builtin_amdgcn_mfma_f32_16x16x32_bf16(af[kk][m], bv[kk][n], acc[m][n], 0, 0, 0);
      __syncthreads();
    }
  }
  // epilogue: C'[d][node]; d = wave*32+m*16+fq*4+r, node = n0 + n*16+fr
  bf16* lds_t = (bf16*)smem;  // [32 node][520 d]
#pragma unroll
  for (int m = 0; m < 2; ++m)
#pragma unroll
    for (int n = 0; n < 2; ++n)
#pragma unroll
      for (int r = 0; r < 4; ++r) {
        int d = wave * 32 + m * 16 + fq * 4 + r;
        int node = n * 16 + fr;
        float v = acc[m][n][r] + bself[d];
        v = v > 0.f ? v : 0.f;
        bf16 h = (bf16)v;
        xbT[(size_t)d * NN + n0 + node] = h;
        lds_t[node * 520 + d] = h;
      }
  __syncthreads();
  {
    int node = tid >> 5;
    int dc = (tid & 31) * 16;
    bf16x8 v0 = *(const bf16x8*)&lds_t[node * 520 + dc];
    bf16x8 v1 = *(const bf16x8*)&lds_t[node * 520 + dc + 8];
    *(bf16x8*)&xb[(size_t)(n0 + node) * DD + dc] = v0;
    *(bf16x8*)&xb[(size_t)(n0 + node) * DD + dc + 8] = v1;
  }
}

// ---------------- pooling + head ----------------

__global__ __launch_bounds__(256) void pool_kernel(
    const bf16* __restrict__ xb, float* __restrict__ pooled) {
  const int t = (int)threadIdx.x;
  const int r0 = (int)blockIdx.x * 32;
  float s0 = 0.f, s1 = 0.f;
  for (int r = 0; r < 32; ++r) {
    s0 += (float)xb[(size_t)(r0 + r) * DD + t];
    s1 += (float)xb[(size_t)(r0 + r) * DD + t + 256];
  }
  atomicAdd(&pooled[t], s0);
  atomicAdd(&pooled[t + 256], s1);
}

__global__ __launch_bounds__(64) void final_kernel(
    const float* __restrict__ pooled, const float* __restrict__ features,
    const float* __restrict__ wfc, const float* __restrict__ bfc,
    float* __restrict__ out) {
  const int t = (int)threadIdx.x;
  float s = 0.f;
  for (int i = t; i < DD + 64; i += 64) {
    float v = (i < DD) ? pooled[i] * (1.0f / (float)NN) : features[i - DD];
    s += v * wfc[i];
  }
#pragma unroll
  for (int off = 32; off > 0; off >>= 1) s += __shfl_down(s, off);
  if (t == 0) {
    float z = s + bfc[0];
    out[0] = 1.0f / (1.0f + expf(-z));
  }
}

// ---------------- launch ----------------

extern "C" void kernel_launch(void* const* d_in, const int* in_sizes, int n_in,
                              void* d_out, int out_size, void* d_ws, size_t ws_size,
                              hipStream_t stream) {
  const float* labels   = (const float*)d_in[0];
  const float* adj      = (const float*)d_in[1];
  const float* features = (const float*)d_in[2];
  const float* W_self   = (const float*)d_in[3];
  const float* b_self   = (const float*)d_in[4];
  const float* W_neigh  = (const float*)d_in[5];
  const float* W_fc     = (const float*)d_in[6];
  const float* b_fc     = (const float*)d_in[7];
  float* out = (float*)d_out;

  char* ws = (char*)d_ws;   // ws_size = 1 GiB (observed); layout needs ~185.6 MB
  bf16*  xb    = (bf16*)(ws);
  bf16*  xbT   = (bf16*)(ws + PSZB);
  bf16*  pbase = (bf16*)(ws + 2 * PSZB);
  char*  after_p = ws + (size_t)(2 + NS) * PSZB;
  bf16*  wsb    = (bf16*)(after_p);
  bf16*  wnb    = (bf16*)(after_p + 524288);
  float* pooled = (float*)(after_p + 1048576);
  bf16*  adjb   = (bf16*)(after_p + 1048576 + 4096);

  convert_w_kernel<<<2 * DD * DD / 8 / 256, 256, 0, stream>>>(W_self, W_neigh, wsb, wnb);
  convert_adj_kernel<<<(int)((size_t)NN * NN / 8 / 256), 256, 0, stream>>>(adj, adjb);
  convert_x_kernel<<<dim3(NN / 64, DD / 64), 256, 0, stream>>>(labels, xb, xbT);

  for (int it = 0; it < 4; ++it) {
    gemm1_kernel<<<256, 512, 0, stream>>>(adjb, xbT, pbase);
    gemm2_kernel<<<NN / 32, 1024, 0, stream>>>(wsb, wnb, xb, pbase, b_self, xbT);
  }

  hipMemsetAsync(pooled, 0, DD * sizeof(float), stream);
  pool_kernel<<<NN / 32, 256, 0, stream>>>(xb, pooled);
  final_kernel<<<1, 64, 0, stream>>>(pooled, features, W_fc, b_fc, out);
}

// Round 8
// 421.604 us; speedup vs baseline: 1.1119x; 1.0667x over previous
//
#include <hip/hip_runtime.h>

typedef __bf16 bf16;
typedef bf16 bf16x8 __attribute__((ext_vector_type(8)));
typedef bf16 bf16x4 __attribute__((ext_vector_type(4)));
typedef float f32x4 __attribute__((ext_vector_type(4)));

constexpr int NN = 8192;   // nodes
constexpr int DD = 512;    // gnn dim
constexpr size_t PSZB = (size_t)NN * DD * 2;   // 8 MB, one bf16 [NN][DD] buffer
constexpr size_t PSZE = (size_t)NN * DD;       // elements
constexpr int NS = 4;                          // split-K factor

static __device__ inline bf16x8 cvt8(const float* __restrict__ p) {
  f32x4 a = *(const f32x4*)p;
  f32x4 b = *(const f32x4*)(p + 4);
  bf16x8 r;
  r[0] = (bf16)a[0]; r[1] = (bf16)a[1]; r[2] = (bf16)a[2]; r[3] = (bf16)a[3];
  r[4] = (bf16)b[0]; r[5] = (bf16)b[1]; r[6] = (bf16)b[2]; r[7] = (bf16)b[3];
  return r;
}

// async global->LDS, 16B per lane, dest = wave-uniform base + lane*16
#define GLDS(g, l) __builtin_amdgcn_global_load_lds( \
    (const __attribute__((address_space(1))) unsigned int*)(const void*)(g), \
    (__attribute__((address_space(3))) unsigned int*)(void*)(l), 16, 0, 0)

// ---------------- converts ----------------

__global__ __launch_bounds__(256) void convert_w_kernel(
    const float* __restrict__ a, const float* __restrict__ b,
    bf16* __restrict__ ao, bf16* __restrict__ bo) {
  int i8 = ((int)blockIdx.x * 256 + (int)threadIdx.x) * 8;
  if (i8 < DD * DD) {
    *(bf16x8*)&ao[i8] = cvt8(a + i8);
  } else {
    int j = i8 - DD * DD;
    *(bf16x8*)&bo[j] = cvt8(b + j);
  }
}

__global__ __launch_bounds__(256) void convert_adj_kernel(
    const float* __restrict__ a, bf16* __restrict__ o) {
  size_t i8 = ((size_t)blockIdx.x * 256 + threadIdx.x) * 8;
  *(bf16x8*)&o[i8] = cvt8(a + i8);
}

// labels f32 [NN][DD] -> xb bf16 [NN][DD] and xbT bf16 [DD][NN] (64x64 LDS tiles)
__global__ __launch_bounds__(256) void convert_x_kernel(
    const float* __restrict__ src, bf16* __restrict__ xb, bf16* __restrict__ xbT) {
  __shared__ __align__(16) float tile[64][68];
  const int tid = (int)threadIdx.x;
  const int r0 = (int)blockIdx.x * 64;
  const int c0 = (int)blockIdx.y * 64;
#pragma unroll
  for (int p = 0; p < 4; ++p) {
    int row = p * 16 + (tid >> 4);
    int col = (tid & 15) * 4;
    *(f32x4*)&tile[row][col] = *(const f32x4*)&src[(size_t)(r0 + row) * DD + c0 + col];
  }
  __syncthreads();
#pragma unroll
  for (int p = 0; p < 4; ++p) {
    int row = p * 16 + (tid >> 4);
    int col = (tid & 15) * 4;
    f32x4 v = *(const f32x4*)&tile[row][col];
    bf16x4 o;
    o[0] = (bf16)v[0]; o[1] = (bf16)v[1]; o[2] = (bf16)v[2]; o[3] = (bf16)v[3];
    *(bf16x4*)&xb[(size_t)(r0 + row) * DD + c0 + col] = o;
  }
  {
    int c = tid >> 2;
    int rp = (tid & 3) * 16;
    bf16x8 o0, o1;
#pragma unroll
    for (int j = 0; j < 8; ++j) o0[j] = (bf16)tile[rp + j][c];
#pragma unroll
    for (int j = 0; j < 8; ++j) o1[j] = (bf16)tile[rp + 8 + j][c];
    *(bf16x8*)&xbT[(size_t)(c0 + c) * NN + r0 + rp] = o0;
    *(bf16x8*)&xbT[(size_t)(c0 + c) * NN + r0 + rp + 8] = o1;
  }
}

// ---------------- GEMM1: P_s = bf16( adjb[:,ks:ke] @ x[ks:ke,:] ) ----------------
// (unchanged from R7 — best known: 2 merged phases, counted vmcnt(6), T2 swizzle)

__device__ __forceinline__ void stage_half(const bf16* __restrict__ g, int grow0, int k0,
                                           bf16* smbase, int wave, int lane) {
#pragma unroll
  for (int i = 0; i < 2; ++i) {
    int c = wave * 2 + i;                                    // chunk 0..15, 1 KB each
    int row = grow0 + c * 8 + (lane >> 3);
    int col = k0 + (((lane & 7) ^ ((lane >> 3) & 7)) << 3);  // pre-swizzled source slot
    GLDS(g + (size_t)row * NN + col, smbase + c * 512);
  }
}

__global__ __launch_bounds__(512, 2)
void gemm1_kernel(const bf16* __restrict__ adjb, const bf16* __restrict__ xbT,
                  bf16* __restrict__ pbase) {
  __shared__ __align__(16) bf16 sm[65536];   // [par][A 16384 | B 16384], 128 KiB
  const int bid  = (int)blockIdx.x;
  const int xcd  = bid & 7, ii = bid >> 3;
  const int cb   = ii & 1;
  const int jj_  = xcd + 8 * (ii >> 1);
  const int p    = jj_ >> 2;
  const int s    = jj_ & 3;
  const int prow0 = p * 256;
  const int bcol0 = cb * 256;
  const int kb    = s * 2048;
  bf16* __restrict__ P = pbase + (size_t)s * PSZE;

  const int tid  = (int)threadIdx.x;
  const int lane = tid & 63;
  const int wave = tid >> 6;            // 0..7
  const int wr   = wave >> 2;           // 0..1
  const int wc   = wave & 3;            // 0..3
  const int fr   = lane & 15, fq = lane >> 4;

  f32x4 acc[8][4] = {};

#define A_OFF(par) ((par) * 32768)
#define B_OFF(par) ((par) * 32768 + 16384)
#define STAGE_A(tile, half, par) \
  stage_half(adjb, prow0 + (half) * 128, kb + ((tile) & 31) * 64, \
             sm + A_OFF(par) + (half) * 8192, wave, lane)
#define STAGE_B(tile, half, par) \
  stage_half(xbT, bcol0 + (half) * 128, kb + ((tile) & 31) * 64, \
             sm + B_OFF(par) + (half) * 8192, wave, lane)
#define BARRIER() __builtin_amdgcn_s_barrier(); __builtin_amdgcn_sched_barrier(0)

  // prologue (14 insts): B(0), Ah0(0), Ah1(0), B(1), Ah0(1)
  STAGE_B(0, 0, 0); STAGE_B(0, 1, 0); STAGE_A(0, 0, 0); STAGE_A(0, 1, 0);
  STAGE_B(1, 0, 1); STAGE_B(1, 1, 1); STAGE_A(1, 0, 1);

  bf16x8 bv[2][4], af[2][2];

#define LOAD_B(par)                                                        \
  _Pragma("unroll") for (int kk = 0; kk < 2; ++kk)                         \
  _Pragma("unroll") for (int n = 0; n < 4; ++n) {                          \
    int rowl = wc * 64 + n * 16 + fr;                                      \
    int slot = (kk * 4 + fq) ^ (rowl & 7);                                 \
    bv[kk][n] = *(const bf16x8*)&sm[B_OFF(par) + rowl * 64 + slot * 8];    \
  }
#define LOAD_A(q, par)                                                     \
  _Pragma("unroll") for (int kk = 0; kk < 2; ++kk)                         \
  _Pragma("unroll") for (int j = 0; j < 2; ++j) {                          \
    int rowl = (q) * 64 + wr * 32 + j * 16 + fr;                           \
    int slot = (kk * 4 + fq) ^ (rowl & 7);                                 \
    af[kk][j] = *(const bf16x8*)&sm[A_OFF(par) + rowl * 64 + slot * 8];    \
  }
#define QMFMA(q)                                                           \
  __builtin_amdgcn_s_setprio(1);                                           \
  _Pragma("unroll") for (int kk = 0; kk < 2; ++kk)                         \
  _Pragma("unroll") for (int j = 0; j < 2; ++j)                            \
  _Pragma("unroll") for (int n = 0; n < 4; ++n)                            \
    acc[2 * (q) + j][n] = __builtin_amdgcn_mfma_f32_16x16x32_bf16(         \
        af[kk][j], bv[kk][n], acc[2 * (q) + j][n], 0, 0, 0);               \
  __builtin_amdgcn_s_setprio(0);

  int par = 0;
  for (int t = 0; t < 32; ++t, par ^= 1) {
    // ---- phase A: B(all) + A q0,q1 ----
    asm volatile("s_waitcnt vmcnt(6)" ::: "memory");
    BARRIER();
    LOAD_B(par);
    LOAD_A(0, par);
    STAGE_A(t + 1, 1, par ^ 1);
    QMFMA(0);
    LOAD_A(1, par);
    QMFMA(1);

    // ---- phase B: A q2,q3 ----
    BARRIER();
    LOAD_A(2, par);
    STAGE_B(t + 2, 0, par);
    STAGE_B(t + 2, 1, par);
    STAGE_A(t + 2, 0, par);
    QMFMA(2);
    LOAD_A(3, par);
    QMFMA(3);
  }

  // epilogue: C/D frag layout col=lane&15, row=(lane>>4)*4+reg
#pragma unroll
  for (int m = 0; m < 8; ++m)
#pragma unroll
    for (int n = 0; n < 4; ++n)
#pragma unroll
      for (int r = 0; r < 4; ++r) {
        int row = prow0 + (m >> 1) * 64 + wr * 32 + (m & 1) * 16 + fq * 4 + r;
        int col = bcol0 + wc * 64 + n * 16 + fr;
        P[(size_t)row * DD + col] = (bf16)acc[m][n][r];
      }
#undef A_OFF
#undef B_OFF
#undef STAGE_A
#undef STAGE_B
#undef LOAD_B
#undef LOAD_A
#undef QMFMA
#undef BARRIER
}

// ---------------- GEMM2 (transposed, pipelined): x_new^T = relu(Ws@x^T + Wn@Psum^T + b)^T --
// M = 512, N = 32-node panel, K = 1024 (16 tiles of 64: pr=t>>3 selects Ws/Wn).
// Double-buffered: stage(t+1) issued before compute(t); fold = T14 issue-early/write-late.
__global__ __launch_bounds__(1024, 4)
void gemm2_kernel(const bf16* __restrict__ wsb, const bf16* __restrict__ wnb,
                  bf16* __restrict__ xb, const bf16* __restrict__ pbase,
                  const float* __restrict__ bself, bf16* __restrict__ xbT) {
  __shared__ __align__(16) char smem[139264];  // A0 @0, A1 @65536, B0 @131072, B1 @135168
  const int tid  = (int)threadIdx.x;
  const int lane = tid & 63;
  const int wave = tid >> 6;             // 0..15 -> d_out rows wave*32..+31
  const int n0 = (int)blockIdx.x * 32;
  const int fr = lane & 15, fq = lane >> 4;
  const int srow = lane >> 3;
  const int scol = ((lane & 7) ^ (srow & 7)) * 8;   // pre-swizzled source slot
  const int fnode = tid >> 3, fks = tid & 7;        // fold indices

  f32x4 acc[2][2] = {};

  // ---- prologue: stage tile 0 (pr=0, k0=0) into buffer 0 ----
  {
    bf16* la = (bf16*)smem;
#pragma unroll
    for (int c = 0; c < 4; ++c) {
      int chunk = wave * 4 + c;
      GLDS(wsb + (size_t)(chunk * 8 + srow) * DD + scol, &la[chunk * 512]);
    }
    if (wave < 4)
      GLDS(xb + (size_t)(n0 + wave * 8 + srow) * DD + scol,
           &((bf16*)(smem + 131072))[wave * 512]);
  }
  asm volatile("s_waitcnt vmcnt(0)" ::: "memory");
  __builtin_amdgcn_s_barrier();

  for (int t = 0; t < 16; ++t) {
    const int par = t & 1;
    bf16* la = (bf16*)(smem + par * 65536);
    bf16* lb = (bf16*)(smem + 131072 + par * 4096);

    // ---- stage t+1 into par^1: GLDS now; fold loads issued (written later) ----
    bf16x8 fv0, fv1, fv2, fv3;
    bool fold = false;
    if (t < 15) {
      const int tn = t + 1, prn = tn >> 3, k0n = (tn & 7) * 64;
      const bf16* __restrict__ An = prn ? wnb : wsb;
      bf16* lan = (bf16*)(smem + (par ^ 1) * 65536);
#pragma unroll
      for (int c = 0; c < 4; ++c) {
        int chunk = wave * 4 + c;
        GLDS(An + (size_t)(chunk * 8 + srow) * DD + k0n + scol, &lan[chunk * 512]);
      }
      if (prn == 0) {
        if (wave < 4)
          GLDS(xb + (size_t)(n0 + wave * 8 + srow) * DD + k0n + scol,
               &((bf16*)(smem + 131072 + (par ^ 1) * 4096))[wave * 512]);
      } else if (tid < 256) {
        fold = true;
        const bf16* p0 = pbase + (size_t)(n0 + fnode) * DD + k0n + fks * 8;
        fv0 = *(const bf16x8*)(p0);
        fv1 = *(const bf16x8*)(p0 + PSZE);
        fv2 = *(const bf16x8*)(p0 + 2 * PSZE);
        fv3 = *(const bf16x8*)(p0 + 3 * PSZE);
      }
    }

    // ---- compute tile t from buffer par ----
    bf16x8 af[2][2], bv[2][2];
#pragma unroll
    for (int kk = 0; kk < 2; ++kk) {
#pragma unroll
      for (int m = 0; m < 2; ++m) {
        int rowl = wave * 32 + m * 16 + fr;
        int slot = (kk * 4 + fq) ^ (rowl & 7);
        af[kk][m] = *(const bf16x8*)&la[rowl * 64 + slot * 8];
      }
#pragma unroll
      for (int n = 0; n < 2; ++n) {
        int rowl = n * 16 + fr;
        int slot = (kk * 4 + fq) ^ (rowl & 7);
        bv[kk][n] = *(const bf16x8*)&lb[rowl * 64 + slot * 8];
      }
    }
#pragma unroll
    for (int kk = 0; kk < 2; ++kk)
#pragma unroll
      for (int m = 0; m < 2; ++m)
#pragma unroll
        for (int n = 0; n < 2; ++n)
          acc[m][n] = __builtin_amdgcn_mfma_f32_16x16x32_bf16(af[kk][m], bv[kk][n], acc[m][n], 0, 0, 0);

    // ---- fold finish: f32-sum of 4 partials, swizzled ds_write into B[par^1] ----
    if (fold) {
      bf16x8 o;
#pragma unroll
      for (int j = 0; j < 8; ++j)
        o[j] = (bf16)((float)fv0[j] + (float)fv1[j] + (float)fv2[j] + (float)fv3[j]);
      *(bf16x8*)&((bf16*)(smem + 131072 + (par ^ 1) * 4096))[fnode * 64 + (fks ^ (fnode & 7)) * 8] = o;
    }

    asm volatile("s_waitcnt vmcnt(0) lgkmcnt(0)" ::: "memory");
    __builtin_amdgcn_s_barrier();
  }

  // epilogue: C'[d][node]; d = wave*32+m*16+fq*4+r, node = n0 + n*16+fr
  bf16* lds_t = (bf16*)smem;  // [32 node][520 d]
#pragma unroll
  for (int m = 0; m < 2; ++m)
#pragma unroll
    for (int n = 0; n < 2; ++n)
#pragma unroll
      for (int r = 0; r < 4; ++r) {
        int d = wave * 32 + m * 16 + fq * 4 + r;
        int node = n * 16 + fr;
        float v = acc[m][n][r] + bself[d];
        v = v > 0.f ? v : 0.f;
        bf16 h = (bf16)v;
        xbT[(size_t)d * NN + n0 + node] = h;
        lds_t[node * 520 + d] = h;
      }
  __syncthreads();
  {
    int node = tid >> 5;
    int dc = (tid & 31) * 16;
    bf16x8 v0 = *(const bf16x8*)&lds_t[node * 520 + dc];
    bf16x8 v1 = *(const bf16x8*)&lds_t[node * 520 + dc + 8];
    *(bf16x8*)&xb[(size_t)(n0 + node) * DD + dc] = v0;
    *(bf16x8*)&xb[(size_t)(n0 + node) * DD + dc + 8] = v1;
  }
}

// ---------------- pooling + head ----------------

__global__ __launch_bounds__(256) void pool_kernel(
    const bf16* __restrict__ xb, float* __restrict__ pooled) {
  const int t = (int)threadIdx.x;
  const int r0 = (int)blockIdx.x * 32;
  float s0 = 0.f, s1 = 0.f;
  for (int r = 0; r < 32; ++r) {
    s0 += (float)xb[(size_t)(r0 + r) * DD + t];
    s1 += (float)xb[(size_t)(r0 + r) * DD + t + 256];
  }
  atomicAdd(&pooled[t], s0);
  atomicAdd(&pooled[t + 256], s1);
}

__global__ __launch_bounds__(64) void final_kernel(
    const float* __restrict__ pooled, const float* __restrict__ features,
    const float* __restrict__ wfc, const float* __restrict__ bfc,
    float* __restrict__ out) {
  const int t = (int)threadIdx.x;
  float s = 0.f;
  for (int i = t; i < DD + 64; i += 64) {
    float v = (i < DD) ? pooled[i] * (1.0f / (float)NN) : features[i - DD];
    s += v * wfc[i];
  }
#pragma unroll
  for (int off = 32; off > 0; off >>= 1) s += __shfl_down(s, off);
  if (t == 0) {
    float z = s + bfc[0];
    out[0] = 1.0f / (1.0f + expf(-z));
  }
}

// ---------------- launch ----------------

extern "C" void kernel_launch(void* const* d_in, const int* in_sizes, int n_in,
                              void* d_out, int out_size, void* d_ws, size_t ws_size,
                              hipStream_t stream) {
  const float* labels   = (const float*)d_in[0];
  const float* adj      = (const float*)d_in[1];
  const float* features = (const float*)d_in[2];
  const float* W_self   = (const float*)d_in[3];
  const float* b_self   = (const float*)d_in[4];
  const float* W_neigh  = (const float*)d_in[5];
  const float* W_fc     = (const float*)d_in[6];
  const float* b_fc     = (const float*)d_in[7];
  float* out = (float*)d_out;

  char* ws = (char*)d_ws;   // ws_size = 1 GiB (observed); layout needs ~185.6 MB
  bf16*  xb    = (bf16*)(ws);
  bf16*  xbT   = (bf16*)(ws + PSZB);
  bf16*  pbase = (bf16*)(ws + 2 * PSZB);
  char*  after_p = ws + (size_t)(2 + NS) * PSZB;
  bf16*  wsb    = (bf16*)(after_p);
  bf16*  wnb    = (bf16*)(after_p + 524288);
  float* pooled = (float*)(after_p + 1048576);
  bf16*  adjb   = (bf16*)(after_p + 1048576 + 4096);

  convert_w_kernel<<<2 * DD * DD / 8 / 256, 256, 0, stream>>>(W_self, W_neigh, wsb, wnb);
  convert_adj_kernel<<<(int)((size_t)NN * NN / 8 / 256), 256, 0, stream>>>(adj, adjb);
  convert_x_kernel<<<dim3(NN / 64, DD / 64), 256, 0, stream>>>(labels, xb, xbT);

  for (int it = 0; it < 4; ++it) {
    gemm1_kernel<<<256, 512, 0, stream>>>(adjb, xbT, pbase);
    gemm2_kernel<<<NN / 32, 1024, 0, stream>>>(wsb, wnb, xb, pbase, b_self, xbT);
  }

  hipMemsetAsync(pooled, 0, DD * sizeof(float), stream);
  pool_kernel<<<NN / 32, 256, 0, stream>>>(xb, pooled);
  final_kernel<<<1, 64, 0, stream>>>(pooled, features, W_fc, b_fc, out);
}

// Round 9
// 411.832 us; speedup vs baseline: 1.1382x; 1.0237x over previous
//
#include <hip/hip_runtime.h>

typedef __bf16 bf16;
typedef bf16 bf16x8 __attribute__((ext_vector_type(8)));
typedef bf16 bf16x4 __attribute__((ext_vector_type(4)));
typedef float f32x4 __attribute__((ext_vector_type(4)));

constexpr int NN = 8192;   // nodes
constexpr int DD = 512;    // gnn dim
constexpr size_t PSZB = (size_t)NN * DD * 2;   // 8 MB, one bf16 [NN][DD] buffer
constexpr size_t PSZE = (size_t)NN * DD;       // elements
constexpr int NS = 4;                          // split-K factor

static __device__ inline bf16x8 cvt8(const float* __restrict__ p) {
  f32x4 a = *(const f32x4*)p;
  f32x4 b = *(const f32x4*)(p + 4);
  bf16x8 r;
  r[0] = (bf16)a[0]; r[1] = (bf16)a[1]; r[2] = (bf16)a[2]; r[3] = (bf16)a[3];
  r[4] = (bf16)b[0]; r[5] = (bf16)b[1]; r[6] = (bf16)b[2]; r[7] = (bf16)b[3];
  return r;
}

// async global->LDS, 16B per lane, dest = wave-uniform base + lane*16
#define GLDS(g, l) __builtin_amdgcn_global_load_lds( \
    (const __attribute__((address_space(1))) unsigned int*)(const void*)(g), \
    (__attribute__((address_space(3))) unsigned int*)(void*)(l), 16, 0, 0)

// ---------------- converts ----------------

__global__ __launch_bounds__(256) void convert_w_kernel(
    const float* __restrict__ a, const float* __restrict__ b,
    bf16* __restrict__ ao, bf16* __restrict__ bo) {
  int i8 = ((int)blockIdx.x * 256 + (int)threadIdx.x) * 8;
  if (i8 < DD * DD) {
    *(bf16x8*)&ao[i8] = cvt8(a + i8);
  } else {
    int j = i8 - DD * DD;
    *(bf16x8*)&bo[j] = cvt8(b + j);
  }
}

__global__ __launch_bounds__(256) void convert_adj_kernel(
    const float* __restrict__ a, bf16* __restrict__ o) {
  size_t i8 = ((size_t)blockIdx.x * 256 + threadIdx.x) * 8;
  *(bf16x8*)&o[i8] = cvt8(a + i8);
}

// labels f32 [NN][DD] -> xb bf16 [NN][DD] and xbT bf16 [DD][NN] (64x64 LDS tiles)
__global__ __launch_bounds__(256) void convert_x_kernel(
    const float* __restrict__ src, bf16* __restrict__ xb, bf16* __restrict__ xbT) {
  __shared__ __align__(16) float tile[64][68];
  const int tid = (int)threadIdx.x;
  const int r0 = (int)blockIdx.x * 64;
  const int c0 = (int)blockIdx.y * 64;
#pragma unroll
  for (int p = 0; p < 4; ++p) {
    int row = p * 16 + (tid >> 4);
    int col = (tid & 15) * 4;
    *(f32x4*)&tile[row][col] = *(const f32x4*)&src[(size_t)(r0 + row) * DD + c0 + col];
  }
  __syncthreads();
#pragma unroll
  for (int p = 0; p < 4; ++p) {
    int row = p * 16 + (tid >> 4);
    int col = (tid & 15) * 4;
    f32x4 v = *(const f32x4*)&tile[row][col];
    bf16x4 o;
    o[0] = (bf16)v[0]; o[1] = (bf16)v[1]; o[2] = (bf16)v[2]; o[3] = (bf16)v[3];
    *(bf16x4*)&xb[(size_t)(r0 + row) * DD + c0 + col] = o;
  }
  {
    int c = tid >> 2;
    int rp = (tid & 3) * 16;
    bf16x8 o0, o1;
#pragma unroll
    for (int j = 0; j < 8; ++j) o0[j] = (bf16)tile[rp + j][c];
#pragma unroll
    for (int j = 0; j < 8; ++j) o1[j] = (bf16)tile[rp + 8 + j][c];
    *(bf16x8*)&xbT[(size_t)(c0 + c) * NN + r0 + rp] = o0;
    *(bf16x8*)&xbT[(size_t)(c0 + c) * NN + r0 + rp + 8] = o1;
  }
}

// ---------------- GEMM1: P_s = bf16( adjb[:,ks:ke] @ x[ks:ke,:] ) ----------------
// BM=BN=256, BK=64, 512 thr (8 waves 2Mx4N), split-K=4, mfma 16x16x32.
// m201-exact 8-phase schedule: per phase {ds_read quadrant (+B at P1/P5) | 1 half-tile
// stage | barrier | lgkmcnt(0) | setprio MFMA x16 | barrier}; vmcnt(8)@P1,P5,
// vmcnt(10)@P3,P7 (derived from stage liveness). T2 swizzle (verified 0-conflict).

__device__ __forceinline__ void stage_half(const bf16* __restrict__ g, int grow0, int k0,
                                           bf16* smbase, int wave, int lane) {
#pragma unroll
  for (int i = 0; i < 2; ++i) {
    int c = wave * 2 + i;                                    // chunk 0..15, 1 KB each
    int row = grow0 + c * 8 + (lane >> 3);
    int col = k0 + (((lane & 7) ^ ((lane >> 3) & 7)) << 3);  // pre-swizzled source slot
    GLDS(g + (size_t)row * NN + col, smbase + c * 512);
  }
}

__global__ __launch_bounds__(512, 2)
void gemm1_kernel(const bf16* __restrict__ adjb, const bf16* __restrict__ xbT,
                  bf16* __restrict__ pbase) {
  __shared__ __align__(16) bf16 sm[65536];   // [par][A 16384 | B 16384], 128 KiB
  const int bid  = (int)blockIdx.x;
  const int xcd  = bid & 7, ii = bid >> 3;
  const int cb   = ii & 1;
  const int jj_  = xcd + 8 * (ii >> 1);
  const int p    = jj_ >> 2;
  const int s    = jj_ & 3;
  const int prow0 = p * 256;
  const int bcol0 = cb * 256;
  const int kb    = s * 2048;
  bf16* __restrict__ P = pbase + (size_t)s * PSZE;

  const int tid  = (int)threadIdx.x;
  const int lane = tid & 63;
  const int wave = tid >> 6;            // 0..7
  const int wr   = wave >> 2;           // 0..1
  const int wc   = wave & 3;            // 0..3
  const int fr   = lane & 15, fq = lane >> 4;

  f32x4 acc[8][4] = {};

#define A_OFF(par) ((par) * 32768)
#define B_OFF(par) ((par) * 32768 + 16384)
#define STAGE_A(tile, half, par) \
  stage_half(adjb, prow0 + (half) * 128, kb + ((tile) & 31) * 64, \
             sm + A_OFF(par) + (half) * 8192, wave, lane)
#define STAGE_B(tile, half, par) \
  stage_half(xbT, bcol0 + (half) * 128, kb + ((tile) & 31) * 64, \
             sm + B_OFF(par) + (half) * 8192, wave, lane)

  // prologue (14 loads): first 6 = B(0)+Ah0(0) [P1's vmcnt(8) target],
  // last 8 = Ah1(0), B(1), Ah0(1).
  STAGE_B(0, 0, 0); STAGE_B(0, 1, 0); STAGE_A(0, 0, 0);
  STAGE_A(0, 1, 0); STAGE_B(1, 0, 1); STAGE_B(1, 1, 1); STAGE_A(1, 0, 1);

  bf16x8 bv[2][4], af[2][2];

#define LOAD_B(par)                                                        \
  _Pragma("unroll") for (int kk = 0; kk < 2; ++kk)                         \
  _Pragma("unroll") for (int n = 0; n < 4; ++n) {                          \
    int rowl = wc * 64 + n * 16 + fr;                                      \
    int slot = (kk * 4 + fq) ^ (rowl & 7);                                 \
    bv[kk][n] = *(const bf16x8*)&sm[B_OFF(par) + rowl * 64 + slot * 8];    \
  }
#define LOAD_A(q, par)                                                     \
  _Pragma("unroll") for (int kk = 0; kk < 2; ++kk)                         \
  _Pragma("unroll") for (int j = 0; j < 2; ++j) {                          \
    int rowl = (q) * 64 + wr * 32 + j * 16 + fr;                           \
    int slot = (kk * 4 + fq) ^ (rowl & 7);                                 \
    af[kk][j] = *(const bf16x8*)&sm[A_OFF(par) + rowl * 64 + slot * 8];    \
  }
#define QMFMA(q)                                                           \
  _Pragma("unroll") for (int kk = 0; kk < 2; ++kk)                         \
  _Pragma("unroll") for (int j = 0; j < 2; ++j)                            \
  _Pragma("unroll") for (int n = 0; n < 4; ++n)                            \
    acc[2 * (q) + j][n] = __builtin_amdgcn_mfma_f32_16x16x32_bf16(         \
        af[kk][j], bv[kk][n], acc[2 * (q) + j][n], 0, 0, 0);
#define PHASE_TAIL(q)                                                      \
  __builtin_amdgcn_s_barrier();                                            \
  asm volatile("s_waitcnt lgkmcnt(0)" ::: "memory");                       \
  __builtin_amdgcn_sched_barrier(0);                                       \
  __builtin_amdgcn_s_setprio(1);                                           \
  QMFMA(q);                                                                \
  __builtin_amdgcn_s_setprio(0);                                           \
  __builtin_amdgcn_s_barrier();

  // stage plan per iteration (tiles t=par0, t+1=par1):
  // P1:Ah1(t+1)->p1  P2:Bh0(t+2)->p0  P3:Bh1(t+2)->p0  P4:Ah0(t+2)->p0
  // P5:Ah1(t+2)->p0  P6:Bh0(t+3)->p1  P7:Bh1(t+3)->p1  P8:Ah0(t+3)->p1
  // each stage's target region was fully ds_read >=1 barrier earlier.
  for (int it = 0; it < 16; ++it) {
    const int t = it * 2;
    // P1: needs B(t)+Ah0(t); 4 newer halves in flight -> vmcnt(8)
    asm volatile("s_waitcnt vmcnt(8)" ::: "memory");
    LOAD_B(0);
    LOAD_A(0, 0);
    STAGE_A(t + 1, 1, 1);
    PHASE_TAIL(0);
    // P2
    LOAD_A(1, 0);
    STAGE_B(t + 2, 0, 0);
    PHASE_TAIL(1);
    // P3: needs Ah1(t); 5 newer halves -> vmcnt(10)
    asm volatile("s_waitcnt vmcnt(10)" ::: "memory");
    LOAD_A(2, 0);
    STAGE_B(t + 2, 1, 0);
    PHASE_TAIL(2);
    // P4
    LOAD_A(3, 0);
    STAGE_A(t + 2, 0, 0);
    PHASE_TAIL(3);
    // P5: needs B(t+1)+Ah0(t+1); 4 newer -> vmcnt(8)
    asm volatile("s_waitcnt vmcnt(8)" ::: "memory");
    LOAD_B(1);
    LOAD_A(0, 1);
    STAGE_A(t + 2, 1, 0);
    PHASE_TAIL(0);
    // P6
    LOAD_A(1, 1);
    STAGE_B(t + 3, 0, 1);
    PHASE_TAIL(1);
    // P7: needs Ah1(t+1) (staged at P1); 5 newer -> vmcnt(10)
    asm volatile("s_waitcnt vmcnt(10)" ::: "memory");
    LOAD_A(2, 1);
    STAGE_B(t + 3, 1, 1);
    PHASE_TAIL(2);
    // P8
    LOAD_A(3, 1);
    STAGE_A(t + 3, 0, 1);
    PHASE_TAIL(3);
  }

  // epilogue: C/D frag layout col=lane&15, row=(lane>>4)*4+reg
#pragma unroll
  for (int m = 0; m < 8; ++m)
#pragma unroll
    for (int n = 0; n < 4; ++n)
#pragma unroll
      for (int r = 0; r < 4; ++r) {
        int row = prow0 + (m >> 1) * 64 + wr * 32 + (m & 1) * 16 + fq * 4 + r;
        int col = bcol0 + wc * 64 + n * 16 + fr;
        P[(size_t)row * DD + col] = (bf16)acc[m][n][r];
      }
#undef A_OFF
#undef B_OFF
#undef STAGE_A
#undef STAGE_B
#undef LOAD_B
#undef LOAD_A
#undef QMFMA
#undef PHASE_TAIL
}

// ---------------- GEMM2 (transposed, pipelined): x_new^T = relu(Ws@x^T + Wn@Psum^T + b)^T --
// M = 512, N = 32-node panel, K = 1024 (16 tiles of 64: pr=t>>3 selects Ws/Wn).
// Double-buffered: stage(t+1) issued before compute(t); fold = T14 issue-early/write-late.
__global__ __launch_bounds__(1024, 4)
void gemm2_kernel(const bf16* __restrict__ wsb, const bf16* __restrict__ wnb,
                  bf16* __restrict__ xb, const bf16* __restrict__ pbase,
                  const float* __restrict__ bself, bf16* __restrict__ xbT) {
  __shared__ __align__(16) char smem[139264];  // A0 @0, A1 @65536, B0 @131072, B1 @135168
  const int tid  = (int)threadIdx.x;
  const int lane = tid & 63;
  const int wave = tid >> 6;             // 0..15 -> d_out rows wave*32..+31
  const int n0 = (int)blockIdx.x * 32;
  const int fr = lane & 15, fq = lane >> 4;
  const int srow = lane >> 3;
  const int scol = ((lane & 7) ^ (srow & 7)) * 8;   // pre-swizzled source slot
  const int fnode = tid >> 3, fks = tid & 7;        // fold indices

  f32x4 acc[2][2] = {};

  // ---- prologue: stage tile 0 (pr=0, k0=0) into buffer 0 ----
  {
    bf16* la = (bf16*)smem;
#pragma unroll
    for (int c = 0; c < 4; ++c) {
      int chunk = wave * 4 + c;
      GLDS(wsb + (size_t)(chunk * 8 + srow) * DD + scol, &la[chunk * 512]);
    }
    if (wave < 4)
      GLDS(xb + (size_t)(n0 + wave * 8 + srow) * DD + scol,
           &((bf16*)(smem + 131072))[wave * 512]);
  }
  asm volatile("s_waitcnt vmcnt(0)" ::: "memory");
  __builtin_amdgcn_s_barrier();

  for (int t = 0; t < 16; ++t) {
    const int par = t & 1;
    bf16* la = (bf16*)(smem + par * 65536);
    bf16* lb = (bf16*)(smem + 131072 + par * 4096);

    // ---- stage t+1 into par^1: GLDS now; fold loads issued (written later) ----
    bf16x8 fv0, fv1, fv2, fv3;
    bool fold = false;
    if (t < 15) {
      const int tn = t + 1, prn = tn >> 3, k0n = (tn & 7) * 64;
      const bf16* __restrict__ An = prn ? wnb : wsb;
      bf16* lan = (bf16*)(smem + (par ^ 1) * 65536);
#pragma unroll
      for (int c = 0; c < 4; ++c) {
        int chunk = wave * 4 + c;
        GLDS(An + (size_t)(chunk * 8 + srow) * DD + k0n + scol, &lan[chunk * 512]);
      }
      if (prn == 0) {
        if (wave < 4)
          GLDS(xb + (size_t)(n0 + wave * 8 + srow) * DD + k0n + scol,
               &((bf16*)(smem + 131072 + (par ^ 1) * 4096))[wave * 512]);
      } else if (tid < 256) {
        fold = true;
        const bf16* p0 = pbase + (size_t)(n0 + fnode) * DD + k0n + fks * 8;
        fv0 = *(const bf16x8*)(p0);
        fv1 = *(const bf16x8*)(p0 + PSZE);
        fv2 = *(const bf16x8*)(p0 + 2 * PSZE);
        fv3 = *(const bf16x8*)(p0 + 3 * PSZE);
      }
    }

    // ---- compute tile t from buffer par ----
    bf16x8 af[2][2], bv[2][2];
#pragma unroll
    for (int kk = 0; kk < 2; ++kk) {
#pragma unroll
      for (int m = 0; m < 2; ++m) {
        int rowl = wave * 32 + m * 16 + fr;
        int slot = (kk * 4 + fq) ^ (rowl & 7);
        af[kk][m] = *(const bf16x8*)&la[rowl * 64 + slot * 8];
      }
#pragma unroll
      for (int n = 0; n < 2; ++n) {
        int rowl = n * 16 + fr;
        int slot = (kk * 4 + fq) ^ (rowl & 7);
        bv[kk][n] = *(const bf16x8*)&lb[rowl * 64 + slot * 8];
      }
    }
#pragma unroll
    for (int kk = 0; kk < 2; ++kk)
#pragma unroll
      for (int m = 0; m < 2; ++m)
#pragma unroll
        for (int n = 0; n < 2; ++n)
          acc[m][n] = __builtin_amdgcn_mfma_f32_16x16x32_bf16(af[kk][m], bv[kk][n], acc[m][n], 0, 0, 0);

    // ---- fold finish: f32-sum of 4 partials, swizzled ds_write into B[par^1] ----
    if (fold) {
      bf16x8 o;
#pragma unroll
      for (int j = 0; j < 8; ++j)
        o[j] = (bf16)((float)fv0[j] + (float)fv1[j] + (float)fv2[j] + (float)fv3[j]);
      *(bf16x8*)&((bf16*)(smem + 131072 + (par ^ 1) * 4096))[fnode * 64 + (fks ^ (fnode & 7)) * 8] = o;
    }

    asm volatile("s_waitcnt vmcnt(0) lgkmcnt(0)" ::: "memory");
    __builtin_amdgcn_s_barrier();
  }

  // epilogue: C'[d][node]; d = wave*32+m*16+fq*4+r, node = n0 + n*16+fr
  bf16* lds_t = (bf16*)smem;  // [32 node][520 d]
#pragma unroll
  for (int m = 0; m < 2; ++m)
#pragma unroll
    for (int n = 0; n < 2; ++n)
#pragma unroll
      for (int r = 0; r < 4; ++r) {
        int d = wave * 32 + m * 16 + fq * 4 + r;
        int node = n * 16 + fr;
        float v = acc[m][n][r] + bself[d];
        v = v > 0.f ? v : 0.f;
        bf16 h = (bf16)v;
        xbT[(size_t)d * NN + n0 + node] = h;
        lds_t[node * 520 + d] = h;
      }
  __syncthreads();
  {
    int node = tid >> 5;
    int dc = (tid & 31) * 16;
    bf16x8 v0 = *(const bf16x8*)&lds_t[node * 520 + dc];
    bf16x8 v1 = *(const bf16x8*)&lds_t[node * 520 + dc + 8];
    *(bf16x8*)&xb[(size_t)(n0 + node) * DD + dc] = v0;
    *(bf16x8*)&xb[(size_t)(n0 + node) * DD + dc + 8] = v1;
  }
}

// ---------------- pooling + head ----------------

__global__ __launch_bounds__(256) void pool_kernel(
    const bf16* __restrict__ xb, float* __restrict__ pooled) {
  const int t = (int)threadIdx.x;
  const int r0 = (int)blockIdx.x * 32;
  float s0 = 0.f, s1 = 0.f;
  for (int r = 0; r < 32; ++r) {
    s0 += (float)xb[(size_t)(r0 + r) * DD + t];
    s1 += (float)xb[(size_t)(r0 + r) * DD + t + 256];
  }
  atomicAdd(&pooled[t], s0);
  atomicAdd(&pooled[t + 256], s1);
}

__global__ __launch_bounds__(64) void final_kernel(
    const float* __restrict__ pooled, const float* __restrict__ features,
    const float* __restrict__ wfc, const float* __restrict__ bfc,
    float* __restrict__ out) {
  const int t = (int)threadIdx.x;
  float s = 0.f;
  for (int i = t; i < DD + 64; i += 64) {
    float v = (i < DD) ? pooled[i] * (1.0f / (float)NN) : features[i - DD];
    s += v * wfc[i];
  }
#pragma unroll
  for (int off = 32; off > 0; off >>= 1) s += __shfl_down(s, off);
  if (t == 0) {
    float z = s + bfc[0];
    out[0] = 1.0f / (1.0f + expf(-z));
  }
}

// ---------------- launch ----------------

extern "C" void kernel_launch(void* const* d_in, const int* in_sizes, int n_in,
                              void* d_out, int out_size, void* d_ws, size_t ws_size,
                              hipStream_t stream) {
  const float* labels   = (const float*)d_in[0];
  const float* adj      = (const float*)d_in[1];
  const float* features = (const float*)d_in[2];
  const float* W_self   = (const float*)d_in[3];
  const float* b_self   = (const float*)d_in[4];
  const float* W_neigh  = (const float*)d_in[5];
  const float* W_fc     = (const float*)d_in[6];
  const float* b_fc     = (const float*)d_in[7];
  float* out = (float*)d_out;

  char* ws = (char*)d_ws;   // ws_size = 1 GiB (observed); layout needs ~185.6 MB
  bf16*  xb    = (bf16*)(ws);
  bf16*  xbT   = (bf16*)(ws + PSZB);
  bf16*  pbase = (bf16*)(ws + 2 * PSZB);
  char*  after_p = ws + (size_t)(2 + NS) * PSZB;
  bf16*  wsb    = (bf16*)(after_p);
  bf16*  wnb    = (bf16*)(after_p + 524288);
  float* pooled = (float*)(after_p + 1048576);
  bf16*  adjb   = (bf16*)(after_p + 1048576 + 4096);

  convert_w_kernel<<<2 * DD * DD / 8 / 256, 256, 0, stream>>>(W_self, W_neigh, wsb, wnb);
  convert_adj_kernel<<<(int)((size_t)NN * NN / 8 / 256), 256, 0, stream>>>(adj, adjb);
  convert_x_kernel<<<dim3(NN / 64, DD / 64), 256, 0, stream>>>(labels, xb, xbT);

  for (int it = 0; it < 4; ++it) {
    gemm1_kernel<<<256, 512, 0, stream>>>(adjb, xbT, pbase);
    gemm2_kernel<<<NN / 32, 1024, 0, stream>>>(wsb, wnb, xb, pbase, b_self, xbT);
  }

  hipMemsetAsync(pooled, 0, DD * sizeof(float), stream);
  pool_kernel<<<NN / 32, 256, 0, stream>>>(xb, pooled);
  final_kernel<<<1, 64, 0, stream>>>(pooled, features, W_fc, b_fc, out);
}